// Round 5
// baseline (311.883 us; speedup 1.0000x reference)
//
#include <hip/hip_runtime.h>
#include <math.h>

#define N_NODES 512
#define SD_ 256
#define VD_ 128
#define ED_ 128
#define NE_ 262144
#define NG_ 16
#define NA_ 16
#define NB_ 5

typedef __attribute__((ext_vector_type(8))) short bf16x8;
typedef __attribute__((ext_vector_type(4))) float f32x4;

__device__ __forceinline__ float silu_f(float x) { return x / (1.0f + expf(-x)); }
__device__ __forceinline__ float silu_fast(float x) {
    return x * __builtin_amdgcn_rcpf(1.0f + __builtin_amdgcn_exp2f(x * -1.44269504f));
}
__device__ __forceinline__ unsigned short f2bf(float x) {
    unsigned int u = __float_as_uint(x);
    return (unsigned short)((u + 0x7fffu + ((u >> 16) & 1u)) >> 16);
}
__device__ __forceinline__ float bf2f(unsigned short h) {
    return __uint_as_float(((unsigned int)h) << 16);
}
__device__ __forceinline__ unsigned int cvt_pk_bf16(float lo, float hi) {
    unsigned int r;
    asm("v_cvt_pk_bf16_f32 %0, %1, %2" : "=v"(r) : "v"(lo), "v"(hi));
    return r;
}

// ---------------- Node phase: 8 nodes per block (W_sm read amortized 8x)
__global__ __launch_bounds__(256) void node_kernel8(
    const float* __restrict__ s, const float* __restrict__ v, const float* __restrict__ p,
    const float* __restrict__ W_sm, const float* __restrict__ b_sm,
    const float* __restrict__ W_a, const float* __restrict__ b_a,
    const float* __restrict__ W_c,
    unsigned short* __restrict__ s2b, float* __restrict__ cpred, float* __restrict__ atoms_out)
{
    const int n0  = blockIdx.x * 8;
    const int tid = threadIdx.x;
    __shared__ float srow[8][SD_];
    __shared__ float s2row[8][SD_];
    #pragma unroll
    for (int n = 0; n < 8; ++n) srow[n][tid] = s[(size_t)(n0 + n) * SD_ + tid];
    __syncthreads();
    float acc[8];
    {
        float bb = b_sm[tid];
        #pragma unroll
        for (int n = 0; n < 8; ++n) acc[n] = bb;
    }
    #pragma unroll 4
    for (int c = 0; c < SD_; ++c) {
        float wv = W_sm[(size_t)c * SD_ + tid];
        #pragma unroll
        for (int n = 0; n < 8; ++n) acc[n] = fmaf(srow[n][c], wv, acc[n]);
    }
    #pragma unroll
    for (int n = 0; n < 8; ++n) {
        float sv = silu_f(acc[n]);
        s2b[(size_t)(n0 + n) * SD_ + tid] = f2bf(sv);
        s2row[n][tid] = sv;
    }
    __syncthreads();
    if (tid < 128) {
        int n = tid >> 4, a = tid & 15;
        float x = b_a[a];
        #pragma unroll 8
        for (int c = 0; c < SD_; ++c) x = fmaf(s2row[n][c], W_a[(size_t)c * NA_ + a], x);
        atoms_out[(size_t)(n0 + n) * NA_ + a] = x;
    } else if (tid < 152) {
        int t = tid - 128;
        int n = t / 3, dd = t % 3;
        float x = p[(n0 + n) * 3 + dd];
        const float* vr = v + (size_t)((n0 + n) * 3 + dd) * VD_;
        #pragma unroll 8
        for (int c = 0; c < VD_; ++c) x = fmaf(vr[c], W_c[c], x);
        cpred[(n0 + n) * 3 + dd] = x;
    }
}

// ---------------- Per-graph mean centering (deterministic serial segment sums)
__global__ __launch_bounds__(512) void center_kernel(
    const float* __restrict__ cpred, const int* __restrict__ batch,
    float* __restrict__ coords_ws, float* __restrict__ coords_out)
{
    __shared__ float cl[N_NODES * 3];
    __shared__ int   bl[N_NODES];
    __shared__ float meanv[NG_ * 3];
    const int tid = threadIdx.x;
    bl[tid] = batch[tid];
    #pragma unroll
    for (int dd = 0; dd < 3; ++dd) cl[tid * 3 + dd] = cpred[tid * 3 + dd];
    __syncthreads();
    if (tid < NG_ * 3) {
        int g = tid / 3, dd = tid % 3;
        float sum = 0.f; int cnt = 0;
        for (int n = 0; n < N_NODES; ++n) {
            if (bl[n] == g) { sum += cl[n * 3 + dd]; cnt++; }
        }
        meanv[tid] = sum / (float)(cnt > 0 ? cnt : 1);
    }
    __syncthreads();
    int g = bl[tid];
    #pragma unroll
    for (int dd = 0; dd < 3; ++dd) {
        float val = cl[tid * 3 + dd] - meanv[g * 3 + dd];
        coords_ws[tid * 3 + dd]  = val;
        coords_out[tid * 3 + dd] = val;
    }
}

// ---------------- fused: last-wins map build (blocks 0..1023) + weight packing (blocks 1024..)
__device__ __forceinline__ void pack_one(
    const float* __restrict__ W, unsigned short* __restrict__ out, int nkb, int idx)
{
    int l = idx & 63;
    int kb = (idx >> 6) % nkb;
    int mtg = idx / (64 * nkb);
    int m = mtg * 16 + (l & 15);
    int k0 = kb * 32 + (l >> 4) * 8;
    bf16x8 pack;
    #pragma unroll
    for (int i = 0; i < 8; ++i) pack[i] = (short)f2bf(W[(size_t)(k0 + i) * SD_ + m]);
    *(bf16x8*)(out + (size_t)idx * 8) = pack;
}

__global__ __launch_bounds__(256) void build_and_pack(
    const int* __restrict__ ei, int* __restrict__ m,
    const float* __restrict__ W_bm, const float* __restrict__ W_b0,
    unsigned short* __restrict__ WfA_bm, unsigned short* __restrict__ WfA_b0)
{
    int bid = blockIdx.x;
    int tid = threadIdx.x;
    if (bid < NE_ / 256) {
        int k = bid * 256 + tid;
        int j = ei[k], i = ei[NE_ + k];
        atomicMax(&m[j * N_NODES + i], k);
    } else {
        int idx = (bid - NE_ / 256) * 256 + tid;   // 0..12287
        if (idx < 4096)  pack_one(W_bm, WfA_bm, 4, idx);
        else             pack_one(W_b0, WfA_b0, 8, idx - 4096);
    }
}

// ---------------- Fused edge pipeline, MFMA version
// R5: esym/fd/bonds_part share ONE 32KB union -> LDS 52.7 -> ~36.4KB -> 4 blocks/CU.
// Cost: +2 barriers (esym-consumed, fd-consumed). Numerics identical to R4.
__global__ __launch_bounds__(256, 4) void edge_mfma(
    const float* __restrict__ e, const int* __restrict__ ei, const int* __restrict__ emap,
    const float* __restrict__ coords, const unsigned short* __restrict__ s2b,
    const unsigned short* __restrict__ WfA_bm, const unsigned short* __restrict__ WfA_b0,
    const float* __restrict__ W_b1,
    const float* __restrict__ b_bm, const float* __restrict__ W_b0_last,
    const float* __restrict__ b_b0, const float* __restrict__ b_b1,
    float* __restrict__ bonds_out)
{
    __shared__ __align__(16) char smem_u[64 * 256 * 2];  // 32KB union: esym(16KB) / fd(32KB) / bonds_part(5KB)
    __shared__ unsigned short wb1t[NB_ * 256];           // 2.5KB bf16, [b][m]
    __shared__ float dw[64];
    __shared__ int li_s[64], lj_s[64];

    unsigned short* esym_lds   = (unsigned short*)smem_u;
    unsigned short* fd_lds_u   = (unsigned short*)smem_u;
    float*          bonds_part = (float*)smem_u;

    const int tid = threadIdx.x;
    const int blk = blockIdx.x;
    const int l   = tid & 63;
    const int w   = tid >> 6;
    const int eLo = l & 15;
    const int hi  = l >> 4;

    // ---- stage W_b1^T (bf16) into LDS
    {
        #pragma unroll
        for (int b = 0; b < NB_; ++b)
            wb1t[b * 256 + tid] = f2bf(W_b1[(size_t)tid * NB_ + b]);
    }

    // ---- meta (wave 0 publishes) + e gather/symmetrize into B-frag LDS layout
    {
        const int eL = l;          // edge-local 0..63
        const int q  = w;          // k-chunk 0..3 (32 k each)
        int ge = blk * 64 + eL;
        int j  = ei[ge], i2 = ei[NE_ + ge];
        int k1 = emap[j * N_NODES + i2];
        int k2 = emap[i2 * N_NODES + j];
        if (w == 0) {
            li_s[eL] = i2; lj_s[eL] = j;
            float dx = coords[i2 * 3 + 0] - coords[j * 3 + 0];
            float dy = coords[i2 * 3 + 1] - coords[j * 3 + 1];
            float dz = coords[i2 * 3 + 2] - coords[j * 3 + 2];
            dw[eL] = dx * dx + dy * dy + dz * dz;
        }
        const float4* p1 = (const float4*)(e + (size_t)k1 * ED_ + q * 32);
        float4 va[8];
        #pragma unroll
        for (int t = 0; t < 8; ++t) va[t] = p1[t];
        if (k2 >= 0) {
            const float4* p2 = (const float4*)(e + (size_t)k2 * ED_ + q * 32);
            #pragma unroll
            for (int t = 0; t < 8; ++t) {
                float4 b4 = p2[t];
                va[t].x += b4.x; va[t].y += b4.y; va[t].z += b4.z; va[t].w += b4.w;
            }
        }
        int ntB = eL >> 4, eLoB = eL & 15;
        #pragma unroll
        for (int h2 = 0; h2 < 4; ++h2) {
            float4 x0 = va[h2 * 2], x1 = va[h2 * 2 + 1];
            uint4 c;
            c.x = cvt_pk_bf16(0.5f * x0.x, 0.5f * x0.y);
            c.y = cvt_pk_bf16(0.5f * x0.z, 0.5f * x0.w);
            c.z = cvt_pk_bf16(0.5f * x1.x, 0.5f * x1.y);
            c.w = cvt_pk_bf16(0.5f * x1.z, 0.5f * x1.w);
            int chunk = (ntB * 4 + q) * 64 + h2 * 16 + eLoB;   // lane-linear: 2-way max
            *(uint4*)(&esym_lds[chunk * 8]) = c;
        }
    }

    // prefetch GEMM1 kb=0 A-frags
    bf16x8 a1p[4];
    #pragma unroll
    for (int mt = 0; mt < 4; ++mt)
        a1p[mt] = *(const bf16x8*)(WfA_bm + ((size_t)(((w * 4 + mt) * 4 + 0) * 64 + l) * 8));

    __syncthreads();   // bar1: esym + meta + wb1t ready

    // ---- GEMM1': K=128 (4 k-steps)
    f32x4 acc[4][4];
    #pragma unroll
    for (int mt = 0; mt < 4; ++mt)
        #pragma unroll
        for (int nt = 0; nt < 4; ++nt) acc[mt][nt] = (f32x4){0.f, 0.f, 0.f, 0.f};

    #pragma unroll
    for (int kb = 0; kb < 4; ++kb) {
        bf16x8 af[4], bfg[4];
        #pragma unroll
        for (int mt = 0; mt < 4; ++mt)
            af[mt] = (kb == 0) ? a1p[mt]
                   : *(const bf16x8*)(WfA_bm + ((size_t)(((w * 4 + mt) * 4 + kb) * 64 + l) * 8));
        #pragma unroll
        for (int nt = 0; nt < 4; ++nt)
            bfg[nt] = *(const bf16x8*)(&esym_lds[(size_t)((nt * 4 + kb) * 64 + l) * 8]);
        __builtin_amdgcn_s_setprio(1);
        #pragma unroll
        for (int mt = 0; mt < 4; ++mt)
            #pragma unroll
            for (int nt = 0; nt < 4; ++nt)
                acc[mt][nt] = __builtin_amdgcn_mfma_f32_16x16x32_bf16(af[mt], bfg[nt], acc[mt][nt], 0, 0, 0);
        __builtin_amdgcn_s_setprio(0);
    }

    // prefetch GEMM2 kb=0 A-frags (global; independent of LDS)
    bf16x8 a2p[4];
    #pragma unroll
    for (int mt = 0; mt < 4; ++mt)
        a2p[mt] = *(const bf16x8*)(WfA_b0 + ((size_t)(((w * 4 + mt) * 8 + 0) * 64 + l) * 8));

    __syncthreads();   // bar1.5: all waves done reading esym (fd overwrites it)

    // ---- epilogue 1: f = acc + s_i + s_j + b_bm -> swizzled fd (bf16)
    #pragma unroll
    for (int mt = 0; mt < 4; ++mt) {
        int m0 = w * 64 + mt * 16 + hi * 4;
        float4 bb = *(const float4*)(b_bm + m0);
        #pragma unroll
        for (int nt = 0; nt < 4; ++nt) {
            int edge = nt * 16 + eLo;
            int ni = li_s[edge], nj = lj_s[edge];
            ushort4 si = *(const ushort4*)(s2b + (size_t)ni * SD_ + m0);
            ushort4 sj = *(const ushort4*)(s2b + (size_t)nj * SD_ + m0);
            f32x4 r = acc[mt][nt];
            float f0 = r[0] + bf2f(si.x) + bf2f(sj.x) + bb.x;
            float f1 = r[1] + bf2f(si.y) + bf2f(sj.y) + bb.y;
            float f2 = r[2] + bf2f(si.z) + bf2f(sj.z) + bb.z;
            float f3 = r[3] + bf2f(si.w) + bf2f(sj.w) + bb.w;
            uint2 pk;
            pk.x = cvt_pk_bf16(f0, f1);
            pk.y = cvt_pk_bf16(f2, f3);
            int c16 = m0 >> 3;                       // 16B granule index 0..31
            int byteo = (edge << 9) + ((c16 ^ (edge & 7)) << 4) + ((m0 & 7) << 1);
            *(uint2*)((char*)fd_lds_u + byteo) = pk;
        }
    }
    __syncthreads();   // bar2: fd ready

    // ---- GEMM2': K=256 (8 k-steps); init = b_b0 + d * W_b0[row 256]
    #pragma unroll
    for (int mt = 0; mt < 4; ++mt) {
        int m0 = w * 64 + mt * 16 + hi * 4;
        float4 b0 = *(const float4*)(b_b0 + m0);
        float4 w2 = *(const float4*)(W_b0_last + m0);
        #pragma unroll
        for (int nt = 0; nt < 4; ++nt) {
            float dd = dw[nt * 16 + eLo];
            acc[mt][nt] = (f32x4){fmaf(dd, w2.x, b0.x), fmaf(dd, w2.y, b0.y),
                                  fmaf(dd, w2.z, b0.z), fmaf(dd, w2.w, b0.w)};
        }
    }
    #pragma unroll
    for (int kb = 0; kb < 8; ++kb) {
        bf16x8 af[4], bfg[4];
        #pragma unroll
        for (int mt = 0; mt < 4; ++mt)
            af[mt] = (kb == 0) ? a2p[mt]
                   : *(const bf16x8*)(WfA_b0 + ((size_t)(((w * 4 + mt) * 8 + kb) * 64 + l) * 8));
        #pragma unroll
        for (int nt = 0; nt < 4; ++nt) {
            int edge = nt * 16 + eLo;
            int c16 = (kb << 2) + hi;
            int byteo = (edge << 9) + ((c16 ^ (edge & 7)) << 4);
            bfg[nt] = *(const bf16x8*)((const char*)fd_lds_u + byteo);
        }
        __builtin_amdgcn_s_setprio(1);
        #pragma unroll
        for (int mt = 0; mt < 4; ++mt)
            #pragma unroll
            for (int nt = 0; nt < 4; ++nt)
                acc[mt][nt] = __builtin_amdgcn_mfma_f32_16x16x32_bf16(af[mt], bfg[nt], acc[mt][nt], 0, 0, 0);
        __builtin_amdgcn_s_setprio(0);
    }

    // ---- bonds: h = silu(pre) fp32, dot with W_b1 (bf16), reduce over m
    float pb[4][NB_];
    #pragma unroll
    for (int nt = 0; nt < 4; ++nt)
        #pragma unroll
        for (int b = 0; b < NB_; ++b) pb[nt][b] = 0.f;
    #pragma unroll
    for (int mt = 0; mt < 4; ++mt) {
        int m0 = w * 64 + mt * 16 + hi * 4;
        ushort4 wv[NB_];
        #pragma unroll
        for (int b = 0; b < NB_; ++b)
            wv[b] = *(const ushort4*)(wb1t + b * 256 + m0);
        #pragma unroll
        for (int nt = 0; nt < 4; ++nt) {
            f32x4 r = acc[mt][nt];
            float h0 = silu_fast(r[0]);
            float h1 = silu_fast(r[1]);
            float h2 = silu_fast(r[2]);
            float h3 = silu_fast(r[3]);
            #pragma unroll
            for (int b = 0; b < NB_; ++b) {
                float t = fmaf(h0, bf2f(wv[b].x), fmaf(h1, bf2f(wv[b].y),
                          fmaf(h2, bf2f(wv[b].z), h3 * bf2f(wv[b].w))));
                pb[nt][b] += t;
            }
        }
    }
    // reduce over hi groups (lanes l, l^16, l^32, l^48 share the same edge column)
    #pragma unroll
    for (int off = 16; off <= 32; off <<= 1)
        #pragma unroll
        for (int nt = 0; nt < 4; ++nt)
            #pragma unroll
            for (int b = 0; b < NB_; ++b)
                pb[nt][b] += __shfl_xor(pb[nt][b], off);

    __syncthreads();   // bar2.5: all waves done reading fd (bonds_part overwrites it)

    if (hi == 0) {
        #pragma unroll
        for (int nt = 0; nt < 4; ++nt)
            #pragma unroll
            for (int b = 0; b < NB_; ++b)
                bonds_part[(size_t)(w * 64 + nt * 16 + eLo) * NB_ + b] = pb[nt][b];
    }
    __syncthreads();   // bar3: bonds_part ready

    // 320 (edge,b) pairs, 256 threads -> strided loop
    for (int idx = tid; idx < 64 * NB_; idx += 256) {
        int edge = idx / NB_, b = idx % NB_;
        float s4 = bonds_part[(size_t)(0 * 64 + edge) * NB_ + b]
                 + bonds_part[(size_t)(1 * 64 + edge) * NB_ + b]
                 + bonds_part[(size_t)(2 * 64 + edge) * NB_ + b]
                 + bonds_part[(size_t)(3 * 64 + edge) * NB_ + b];
        bonds_out[(size_t)(blk * 64 + edge) * NB_ + b] = s4 + b_b1[b];
    }
}

extern "C" void kernel_launch(void* const* d_in, const int* in_sizes, int n_in,
                              void* d_out, int out_size, void* d_ws, size_t ws_size,
                              hipStream_t stream)
{
    const float* s    = (const float*)d_in[0];
    const float* v    = (const float*)d_in[1];
    const float* p    = (const float*)d_in[2];
    const float* e    = (const float*)d_in[3];
    const int*   batch= (const int*)d_in[4];
    const int*   ei   = (const int*)d_in[5];
    const float* W_sm = (const float*)d_in[6];
    const float* b_sm = (const float*)d_in[7];
    const float* W_bm = (const float*)d_in[8];
    const float* b_bm = (const float*)d_in[9];
    const float* W_b0 = (const float*)d_in[10];
    const float* b_b0 = (const float*)d_in[11];
    const float* W_b1 = (const float*)d_in[12];
    const float* b_b1 = (const float*)d_in[13];
    const float* W_c  = (const float*)d_in[14];
    const float* W_a  = (const float*)d_in[15];
    const float* b_a  = (const float*)d_in[16];

    float* out = (float*)d_out;
    float* coords_out = out;                       // 512*3
    float* atoms_out  = out + 1536;                // 512*16
    float* bonds_out  = out + 1536 + 8192;         // 262144*5

    char* ws = (char*)d_ws;
    int*            emap    = (int*)ws;                                  // @0, 1 MB
    unsigned short* s2b     = (unsigned short*)(ws + 0x100000);          // 256 KB
    unsigned short* WfA_bm  = (unsigned short*)(ws + 0x140000);          // 64 KB
    unsigned short* WfA_b0  = (unsigned short*)(ws + 0x150000);          // 128 KB
    float*          cpred   = (float*)(ws + 0x170000);                   // 6 KB
    float*          coords  = (float*)(ws + 0x172000);                   // 6 KB

    hipMemsetAsync(emap, 0xFF, N_NODES * N_NODES * sizeof(int), stream); // emap = -1

    build_and_pack<<<NE_ / 256 + 48, 256, 0, stream>>>(ei, emap, W_bm, W_b0, WfA_bm, WfA_b0);
    node_kernel8<<<N_NODES / 8, 256, 0, stream>>>(s, v, p, W_sm, b_sm, W_a, b_a, W_c,
                                                  s2b, cpred, atoms_out);
    center_kernel<<<1, 512, 0, stream>>>(cpred, batch, coords, coords_out);

    edge_mfma<<<NE_ / 64, 256, 0, stream>>>(e, ei, emap, coords, s2b,
                                            WfA_bm, WfA_b0, W_b1,
                                            b_bm, W_b0 + 256 * SD_, b_b0, b_b1,
                                            bonds_out);
}

// Round 6
// 283.063 us; speedup vs baseline: 1.1018x; 1.1018x over previous
//
#include <hip/hip_runtime.h>
#include <math.h>

#define N_NODES 512
#define SD_ 256
#define VD_ 128
#define ED_ 128
#define NE_ 262144
#define NG_ 16
#define NA_ 16
#define NB_ 5

typedef __attribute__((ext_vector_type(8))) short bf16x8;
typedef __attribute__((ext_vector_type(4))) float f32x4;

__device__ __forceinline__ float silu_f(float x) { return x / (1.0f + expf(-x)); }
__device__ __forceinline__ float silu_fast(float x) {
    return x * __builtin_amdgcn_rcpf(1.0f + __builtin_amdgcn_exp2f(x * -1.44269504f));
}
__device__ __forceinline__ unsigned short f2bf(float x) {
    unsigned int u = __float_as_uint(x);
    return (unsigned short)((u + 0x7fffu + ((u >> 16) & 1u)) >> 16);
}
__device__ __forceinline__ float bf2f(unsigned short h) {
    return __uint_as_float(((unsigned int)h) << 16);
}
__device__ __forceinline__ unsigned int cvt_pk_bf16(float lo, float hi) {
    unsigned int r;
    asm("v_cvt_pk_bf16_f32 %0, %1, %2" : "=v"(r) : "v"(lo), "v"(hi));
    return r;
}

// ---------------- Node phase: 8 nodes per block (W_sm read amortized 8x)
__global__ __launch_bounds__(256) void node_kernel8(
    const float* __restrict__ s, const float* __restrict__ v, const float* __restrict__ p,
    const float* __restrict__ W_sm, const float* __restrict__ b_sm,
    const float* __restrict__ W_a, const float* __restrict__ b_a,
    const float* __restrict__ W_c,
    unsigned short* __restrict__ s2b, float* __restrict__ cpred, float* __restrict__ atoms_out)
{
    const int n0  = blockIdx.x * 8;
    const int tid = threadIdx.x;
    __shared__ float srow[8][SD_];
    __shared__ float s2row[8][SD_];
    #pragma unroll
    for (int n = 0; n < 8; ++n) srow[n][tid] = s[(size_t)(n0 + n) * SD_ + tid];
    __syncthreads();
    float acc[8];
    {
        float bb = b_sm[tid];
        #pragma unroll
        for (int n = 0; n < 8; ++n) acc[n] = bb;
    }
    #pragma unroll 4
    for (int c = 0; c < SD_; ++c) {
        float wv = W_sm[(size_t)c * SD_ + tid];
        #pragma unroll
        for (int n = 0; n < 8; ++n) acc[n] = fmaf(srow[n][c], wv, acc[n]);
    }
    #pragma unroll
    for (int n = 0; n < 8; ++n) {
        float sv = silu_f(acc[n]);
        s2b[(size_t)(n0 + n) * SD_ + tid] = f2bf(sv);
        s2row[n][tid] = sv;
    }
    __syncthreads();
    if (tid < 128) {
        int n = tid >> 4, a = tid & 15;
        float x = b_a[a];
        #pragma unroll 8
        for (int c = 0; c < SD_; ++c) x = fmaf(s2row[n][c], W_a[(size_t)c * NA_ + a], x);
        atoms_out[(size_t)(n0 + n) * NA_ + a] = x;
    } else if (tid < 152) {
        int t = tid - 128;
        int n = t / 3, dd = t % 3;
        float x = p[(n0 + n) * 3 + dd];
        const float* vr = v + (size_t)((n0 + n) * 3 + dd) * VD_;
        #pragma unroll 8
        for (int c = 0; c < VD_; ++c) x = fmaf(vr[c], W_c[c], x);
        cpred[(n0 + n) * 3 + dd] = x;
    }
}

// ---------------- Per-graph mean centering (deterministic serial segment sums)
__global__ __launch_bounds__(512) void center_kernel(
    const float* __restrict__ cpred, const int* __restrict__ batch,
    float* __restrict__ coords_ws, float* __restrict__ coords_out)
{
    __shared__ float cl[N_NODES * 3];
    __shared__ int   bl[N_NODES];
    __shared__ float meanv[NG_ * 3];
    const int tid = threadIdx.x;
    bl[tid] = batch[tid];
    #pragma unroll
    for (int dd = 0; dd < 3; ++dd) cl[tid * 3 + dd] = cpred[tid * 3 + dd];
    __syncthreads();
    if (tid < NG_ * 3) {
        int g = tid / 3, dd = tid % 3;
        float sum = 0.f; int cnt = 0;
        for (int n = 0; n < N_NODES; ++n) {
            if (bl[n] == g) { sum += cl[n * 3 + dd]; cnt++; }
        }
        meanv[tid] = sum / (float)(cnt > 0 ? cnt : 1);
    }
    __syncthreads();
    int g = bl[tid];
    #pragma unroll
    for (int dd = 0; dd < 3; ++dd) {
        float val = cl[tid * 3 + dd] - meanv[g * 3 + dd];
        coords_ws[tid * 3 + dd]  = val;
        coords_out[tid * 3 + dd] = val;
    }
}

// ---------------- fused: last-wins map build (blocks 0..1023) + weight packing (blocks 1024..)
__device__ __forceinline__ void pack_one(
    const float* __restrict__ W, unsigned short* __restrict__ out, int nkb, int idx)
{
    int l = idx & 63;
    int kb = (idx >> 6) % nkb;
    int mtg = idx / (64 * nkb);
    int m = mtg * 16 + (l & 15);
    int k0 = kb * 32 + (l >> 4) * 8;
    bf16x8 pack;
    #pragma unroll
    for (int i = 0; i < 8; ++i) pack[i] = (short)f2bf(W[(size_t)(k0 + i) * SD_ + m]);
    *(bf16x8*)(out + (size_t)idx * 8) = pack;
}

__global__ __launch_bounds__(256) void build_and_pack(
    const int* __restrict__ ei, int* __restrict__ m,
    const float* __restrict__ W_bm, const float* __restrict__ W_b0,
    unsigned short* __restrict__ WfA_bm, unsigned short* __restrict__ WfA_b0)
{
    int bid = blockIdx.x;
    int tid = threadIdx.x;
    if (bid < NE_ / 256) {
        int k = bid * 256 + tid;
        int j = ei[k], i = ei[NE_ + k];
        atomicMax(&m[j * N_NODES + i], k);
    } else {
        int idx = (bid - NE_ / 256) * 256 + tid;   // 0..12287
        if (idx < 4096)  pack_one(W_bm, WfA_bm, 4, idx);
        else             pack_one(W_b0, WfA_b0, 8, idx - 4096);
    }
}

// ---------------- Fused edge pipeline, MFMA version
// R6: LDS union (36.4KB -> 4 blocks/CU) kept from R5; launch_bounds min-waves pin
// DROPPED (R5 lesson: pinning to 4 waves/EU forced VGPR 64 -> scratch spills,
// FETCH 124->362MB). Natural 128 VGPR also allows exactly 4 waves/SIMD.
__global__ __launch_bounds__(256) void edge_mfma(
    const float* __restrict__ e, const int* __restrict__ ei, const int* __restrict__ emap,
    const float* __restrict__ coords, const unsigned short* __restrict__ s2b,
    const unsigned short* __restrict__ WfA_bm, const unsigned short* __restrict__ WfA_b0,
    const float* __restrict__ W_b1,
    const float* __restrict__ b_bm, const float* __restrict__ W_b0_last,
    const float* __restrict__ b_b0, const float* __restrict__ b_b1,
    float* __restrict__ bonds_out)
{
    __shared__ __align__(16) char smem_u[64 * 256 * 2];  // 32KB union: esym(16KB) / fd(32KB) / bonds_part(5KB)
    __shared__ unsigned short wb1t[NB_ * 256];           // 2.5KB bf16, [b][m]
    __shared__ float dw[64];
    __shared__ int li_s[64], lj_s[64];

    unsigned short* esym_lds   = (unsigned short*)smem_u;
    unsigned short* fd_lds_u   = (unsigned short*)smem_u;
    float*          bonds_part = (float*)smem_u;

    const int tid = threadIdx.x;
    const int blk = blockIdx.x;
    const int l   = tid & 63;
    const int w   = tid >> 6;
    const int eLo = l & 15;
    const int hi  = l >> 4;

    // ---- stage W_b1^T (bf16) into LDS
    {
        #pragma unroll
        for (int b = 0; b < NB_; ++b)
            wb1t[b * 256 + tid] = f2bf(W_b1[(size_t)tid * NB_ + b]);
    }

    // ---- meta (wave 0 publishes) + e gather/symmetrize into B-frag LDS layout
    {
        const int eL = l;          // edge-local 0..63
        const int q  = w;          // k-chunk 0..3 (32 k each)
        int ge = blk * 64 + eL;
        int j  = ei[ge], i2 = ei[NE_ + ge];
        int k1 = emap[j * N_NODES + i2];
        int k2 = emap[i2 * N_NODES + j];
        if (w == 0) {
            li_s[eL] = i2; lj_s[eL] = j;
            float dx = coords[i2 * 3 + 0] - coords[j * 3 + 0];
            float dy = coords[i2 * 3 + 1] - coords[j * 3 + 1];
            float dz = coords[i2 * 3 + 2] - coords[j * 3 + 2];
            dw[eL] = dx * dx + dy * dy + dz * dz;
        }
        const float4* p1 = (const float4*)(e + (size_t)k1 * ED_ + q * 32);
        float4 va[8];
        #pragma unroll
        for (int t = 0; t < 8; ++t) va[t] = p1[t];
        if (k2 >= 0) {
            const float4* p2 = (const float4*)(e + (size_t)k2 * ED_ + q * 32);
            #pragma unroll
            for (int t = 0; t < 8; ++t) {
                float4 b4 = p2[t];
                va[t].x += b4.x; va[t].y += b4.y; va[t].z += b4.z; va[t].w += b4.w;
            }
        }
        int ntB = eL >> 4, eLoB = eL & 15;
        #pragma unroll
        for (int h2 = 0; h2 < 4; ++h2) {
            float4 x0 = va[h2 * 2], x1 = va[h2 * 2 + 1];
            uint4 c;
            c.x = cvt_pk_bf16(0.5f * x0.x, 0.5f * x0.y);
            c.y = cvt_pk_bf16(0.5f * x0.z, 0.5f * x0.w);
            c.z = cvt_pk_bf16(0.5f * x1.x, 0.5f * x1.y);
            c.w = cvt_pk_bf16(0.5f * x1.z, 0.5f * x1.w);
            int chunk = (ntB * 4 + q) * 64 + h2 * 16 + eLoB;   // lane-linear: 2-way max
            *(uint4*)(&esym_lds[chunk * 8]) = c;
        }
    }

    // prefetch GEMM1 kb=0 A-frags
    bf16x8 a1p[4];
    #pragma unroll
    for (int mt = 0; mt < 4; ++mt)
        a1p[mt] = *(const bf16x8*)(WfA_bm + ((size_t)(((w * 4 + mt) * 4 + 0) * 64 + l) * 8));

    __syncthreads();   // bar1: esym + meta + wb1t ready

    // ---- GEMM1': K=128 (4 k-steps)
    f32x4 acc[4][4];
    #pragma unroll
    for (int mt = 0; mt < 4; ++mt)
        #pragma unroll
        for (int nt = 0; nt < 4; ++nt) acc[mt][nt] = (f32x4){0.f, 0.f, 0.f, 0.f};

    #pragma unroll
    for (int kb = 0; kb < 4; ++kb) {
        bf16x8 af[4], bfg[4];
        #pragma unroll
        for (int mt = 0; mt < 4; ++mt)
            af[mt] = (kb == 0) ? a1p[mt]
                   : *(const bf16x8*)(WfA_bm + ((size_t)(((w * 4 + mt) * 4 + kb) * 64 + l) * 8));
        #pragma unroll
        for (int nt = 0; nt < 4; ++nt)
            bfg[nt] = *(const bf16x8*)(&esym_lds[(size_t)((nt * 4 + kb) * 64 + l) * 8]);
        __builtin_amdgcn_s_setprio(1);
        #pragma unroll
        for (int mt = 0; mt < 4; ++mt)
            #pragma unroll
            for (int nt = 0; nt < 4; ++nt)
                acc[mt][nt] = __builtin_amdgcn_mfma_f32_16x16x32_bf16(af[mt], bfg[nt], acc[mt][nt], 0, 0, 0);
        __builtin_amdgcn_s_setprio(0);
    }

    // prefetch GEMM2 kb=0 A-frags (global; independent of LDS)
    bf16x8 a2p[4];
    #pragma unroll
    for (int mt = 0; mt < 4; ++mt)
        a2p[mt] = *(const bf16x8*)(WfA_b0 + ((size_t)(((w * 4 + mt) * 8 + 0) * 64 + l) * 8));

    __syncthreads();   // bar1.5: all waves done reading esym (fd overwrites it)

    // ---- epilogue 1: f = acc + s_i + s_j + b_bm -> swizzled fd (bf16)
    #pragma unroll
    for (int mt = 0; mt < 4; ++mt) {
        int m0 = w * 64 + mt * 16 + hi * 4;
        float4 bb = *(const float4*)(b_bm + m0);
        #pragma unroll
        for (int nt = 0; nt < 4; ++nt) {
            int edge = nt * 16 + eLo;
            int ni = li_s[edge], nj = lj_s[edge];
            ushort4 si = *(const ushort4*)(s2b + (size_t)ni * SD_ + m0);
            ushort4 sj = *(const ushort4*)(s2b + (size_t)nj * SD_ + m0);
            f32x4 r = acc[mt][nt];
            float f0 = r[0] + bf2f(si.x) + bf2f(sj.x) + bb.x;
            float f1 = r[1] + bf2f(si.y) + bf2f(sj.y) + bb.y;
            float f2 = r[2] + bf2f(si.z) + bf2f(sj.z) + bb.z;
            float f3 = r[3] + bf2f(si.w) + bf2f(sj.w) + bb.w;
            uint2 pk;
            pk.x = cvt_pk_bf16(f0, f1);
            pk.y = cvt_pk_bf16(f2, f3);
            int c16 = m0 >> 3;                       // 16B granule index 0..31
            int byteo = (edge << 9) + ((c16 ^ (edge & 7)) << 4) + ((m0 & 7) << 1);
            *(uint2*)((char*)fd_lds_u + byteo) = pk;
        }
    }
    __syncthreads();   // bar2: fd ready

    // ---- GEMM2': K=256 (8 k-steps); init = b_b0 + d * W_b0[row 256]
    #pragma unroll
    for (int mt = 0; mt < 4; ++mt) {
        int m0 = w * 64 + mt * 16 + hi * 4;
        float4 b0 = *(const float4*)(b_b0 + m0);
        float4 w2 = *(const float4*)(W_b0_last + m0);
        #pragma unroll
        for (int nt = 0; nt < 4; ++nt) {
            float dd = dw[nt * 16 + eLo];
            acc[mt][nt] = (f32x4){fmaf(dd, w2.x, b0.x), fmaf(dd, w2.y, b0.y),
                                  fmaf(dd, w2.z, b0.z), fmaf(dd, w2.w, b0.w)};
        }
    }
    #pragma unroll
    for (int kb = 0; kb < 8; ++kb) {
        bf16x8 af[4], bfg[4];
        #pragma unroll
        for (int mt = 0; mt < 4; ++mt)
            af[mt] = (kb == 0) ? a2p[mt]
                   : *(const bf16x8*)(WfA_b0 + ((size_t)(((w * 4 + mt) * 8 + kb) * 64 + l) * 8));
        #pragma unroll
        for (int nt = 0; nt < 4; ++nt) {
            int edge = nt * 16 + eLo;
            int c16 = (kb << 2) + hi;
            int byteo = (edge << 9) + ((c16 ^ (edge & 7)) << 4);
            bfg[nt] = *(const bf16x8*)((const char*)fd_lds_u + byteo);
        }
        __builtin_amdgcn_s_setprio(1);
        #pragma unroll
        for (int mt = 0; mt < 4; ++mt)
            #pragma unroll
            for (int nt = 0; nt < 4; ++nt)
                acc[mt][nt] = __builtin_amdgcn_mfma_f32_16x16x32_bf16(af[mt], bfg[nt], acc[mt][nt], 0, 0, 0);
        __builtin_amdgcn_s_setprio(0);
    }

    // ---- bonds: h = silu(pre) fp32, dot with W_b1 (bf16), reduce over m
    float pb[4][NB_];
    #pragma unroll
    for (int nt = 0; nt < 4; ++nt)
        #pragma unroll
        for (int b = 0; b < NB_; ++b) pb[nt][b] = 0.f;
    #pragma unroll
    for (int mt = 0; mt < 4; ++mt) {
        int m0 = w * 64 + mt * 16 + hi * 4;
        ushort4 wv[NB_];
        #pragma unroll
        for (int b = 0; b < NB_; ++b)
            wv[b] = *(const ushort4*)(wb1t + b * 256 + m0);
        #pragma unroll
        for (int nt = 0; nt < 4; ++nt) {
            f32x4 r = acc[mt][nt];
            float h0 = silu_fast(r[0]);
            float h1 = silu_fast(r[1]);
            float h2 = silu_fast(r[2]);
            float h3 = silu_fast(r[3]);
            #pragma unroll
            for (int b = 0; b < NB_; ++b) {
                float t = fmaf(h0, bf2f(wv[b].x), fmaf(h1, bf2f(wv[b].y),
                          fmaf(h2, bf2f(wv[b].z), h3 * bf2f(wv[b].w))));
                pb[nt][b] += t;
            }
        }
    }
    // reduce over hi groups (lanes l, l^16, l^32, l^48 share the same edge column)
    #pragma unroll
    for (int off = 16; off <= 32; off <<= 1)
        #pragma unroll
        for (int nt = 0; nt < 4; ++nt)
            #pragma unroll
            for (int b = 0; b < NB_; ++b)
                pb[nt][b] += __shfl_xor(pb[nt][b], off);

    __syncthreads();   // bar2.5: all waves done reading fd (bonds_part overwrites it)

    if (hi == 0) {
        #pragma unroll
        for (int nt = 0; nt < 4; ++nt)
            #pragma unroll
            for (int b = 0; b < NB_; ++b)
                bonds_part[(size_t)(w * 64 + nt * 16 + eLo) * NB_ + b] = pb[nt][b];
    }
    __syncthreads();   // bar3: bonds_part ready

    // 320 (edge,b) pairs, 256 threads -> strided loop
    for (int idx = tid; idx < 64 * NB_; idx += 256) {
        int edge = idx / NB_, b = idx % NB_;
        float s4 = bonds_part[(size_t)(0 * 64 + edge) * NB_ + b]
                 + bonds_part[(size_t)(1 * 64 + edge) * NB_ + b]
                 + bonds_part[(size_t)(2 * 64 + edge) * NB_ + b]
                 + bonds_part[(size_t)(3 * 64 + edge) * NB_ + b];
        bonds_out[(size_t)(blk * 64 + edge) * NB_ + b] = s4 + b_b1[b];
    }
}

extern "C" void kernel_launch(void* const* d_in, const int* in_sizes, int n_in,
                              void* d_out, int out_size, void* d_ws, size_t ws_size,
                              hipStream_t stream)
{
    const float* s    = (const float*)d_in[0];
    const float* v    = (const float*)d_in[1];
    const float* p    = (const float*)d_in[2];
    const float* e    = (const float*)d_in[3];
    const int*   batch= (const int*)d_in[4];
    const int*   ei   = (const int*)d_in[5];
    const float* W_sm = (const float*)d_in[6];
    const float* b_sm = (const float*)d_in[7];
    const float* W_bm = (const float*)d_in[8];
    const float* b_bm = (const float*)d_in[9];
    const float* W_b0 = (const float*)d_in[10];
    const float* b_b0 = (const float*)d_in[11];
    const float* W_b1 = (const float*)d_in[12];
    const float* b_b1 = (const float*)d_in[13];
    const float* W_c  = (const float*)d_in[14];
    const float* W_a  = (const float*)d_in[15];
    const float* b_a  = (const float*)d_in[16];

    float* out = (float*)d_out;
    float* coords_out = out;                       // 512*3
    float* atoms_out  = out + 1536;                // 512*16
    float* bonds_out  = out + 1536 + 8192;         // 262144*5

    char* ws = (char*)d_ws;
    int*            emap    = (int*)ws;                                  // @0, 1 MB
    unsigned short* s2b     = (unsigned short*)(ws + 0x100000);          // 256 KB
    unsigned short* WfA_bm  = (unsigned short*)(ws + 0x140000);          // 64 KB
    unsigned short* WfA_b0  = (unsigned short*)(ws + 0x150000);          // 128 KB
    float*          cpred   = (float*)(ws + 0x170000);                   // 6 KB
    float*          coords  = (float*)(ws + 0x172000);                   // 6 KB

    hipMemsetAsync(emap, 0xFF, N_NODES * N_NODES * sizeof(int), stream); // emap = -1

    build_and_pack<<<NE_ / 256 + 48, 256, 0, stream>>>(ei, emap, W_bm, W_b0, WfA_bm, WfA_b0);
    node_kernel8<<<N_NODES / 8, 256, 0, stream>>>(s, v, p, W_sm, b_sm, W_a, b_a, W_c,
                                                  s2b, cpred, atoms_out);
    center_kernel<<<1, 512, 0, stream>>>(cpred, batch, coords, coords_out);

    edge_mfma<<<NE_ / 64, 256, 0, stream>>>(e, ei, emap, coords, s2b,
                                            WfA_bm, WfA_b0, W_b1,
                                            b_bm, W_b0 + 256 * SD_, b_b0, b_b1,
                                            bonds_out);
}

// Round 7
// 241.784 us; speedup vs baseline: 1.2899x; 1.1707x over previous
//
#include <hip/hip_runtime.h>
#include <math.h>

#define N_NODES 512
#define SD_ 256
#define VD_ 128
#define ED_ 128
#define NE_ 262144
#define NG_ 16
#define NA_ 16
#define NB_ 5

typedef __attribute__((ext_vector_type(8))) short bf16x8;
typedef __attribute__((ext_vector_type(4))) float f32x4;

__device__ __forceinline__ float silu_f(float x) { return x / (1.0f + expf(-x)); }
__device__ __forceinline__ float silu_fast(float x) {
    return x * __builtin_amdgcn_rcpf(1.0f + __builtin_amdgcn_exp2f(x * -1.44269504f));
}
__device__ __forceinline__ unsigned short f2bf(float x) {
    unsigned int u = __float_as_uint(x);
    return (unsigned short)((u + 0x7fffu + ((u >> 16) & 1u)) >> 16);
}
__device__ __forceinline__ float bf2f(unsigned short h) {
    return __uint_as_float(((unsigned int)h) << 16);
}
__device__ __forceinline__ unsigned int cvt_pk_bf16(float lo, float hi) {
    unsigned int r;
    asm("v_cvt_pk_bf16_f32 %0, %1, %2" : "=v"(r) : "v"(lo), "v"(hi));
    return r;
}

// ---------------- Node phase: 8 nodes per block (W_sm read amortized 8x)
__global__ __launch_bounds__(256) void node_kernel8(
    const float* __restrict__ s, const float* __restrict__ v, const float* __restrict__ p,
    const float* __restrict__ W_sm, const float* __restrict__ b_sm,
    const float* __restrict__ W_a, const float* __restrict__ b_a,
    const float* __restrict__ W_c,
    unsigned short* __restrict__ s2b, float* __restrict__ cpred, float* __restrict__ atoms_out)
{
    const int n0  = blockIdx.x * 8;
    const int tid = threadIdx.x;
    __shared__ float srow[8][SD_];
    __shared__ float s2row[8][SD_];
    #pragma unroll
    for (int n = 0; n < 8; ++n) srow[n][tid] = s[(size_t)(n0 + n) * SD_ + tid];
    __syncthreads();
    float acc[8];
    {
        float bb = b_sm[tid];
        #pragma unroll
        for (int n = 0; n < 8; ++n) acc[n] = bb;
    }
    #pragma unroll 4
    for (int c = 0; c < SD_; ++c) {
        float wv = W_sm[(size_t)c * SD_ + tid];
        #pragma unroll
        for (int n = 0; n < 8; ++n) acc[n] = fmaf(srow[n][c], wv, acc[n]);
    }
    #pragma unroll
    for (int n = 0; n < 8; ++n) {
        float sv = silu_f(acc[n]);
        s2b[(size_t)(n0 + n) * SD_ + tid] = f2bf(sv);
        s2row[n][tid] = sv;
    }
    __syncthreads();
    if (tid < 128) {
        int n = tid >> 4, a = tid & 15;
        float x = b_a[a];
        #pragma unroll 8
        for (int c = 0; c < SD_; ++c) x = fmaf(s2row[n][c], W_a[(size_t)c * NA_ + a], x);
        atoms_out[(size_t)(n0 + n) * NA_ + a] = x;
    } else if (tid < 152) {
        int t = tid - 128;
        int n = t / 3, dd = t % 3;
        float x = p[(n0 + n) * 3 + dd];
        const float* vr = v + (size_t)((n0 + n) * 3 + dd) * VD_;
        #pragma unroll 8
        for (int c = 0; c < VD_; ++c) x = fmaf(vr[c], W_c[c], x);
        cpred[(n0 + n) * 3 + dd] = x;
    }
}

// ---------------- Per-graph mean centering (deterministic serial segment sums)
__global__ __launch_bounds__(512) void center_kernel(
    const float* __restrict__ cpred, const int* __restrict__ batch,
    float* __restrict__ coords_ws, float* __restrict__ coords_out)
{
    __shared__ float cl[N_NODES * 3];
    __shared__ int   bl[N_NODES];
    __shared__ float meanv[NG_ * 3];
    const int tid = threadIdx.x;
    bl[tid] = batch[tid];
    #pragma unroll
    for (int dd = 0; dd < 3; ++dd) cl[tid * 3 + dd] = cpred[tid * 3 + dd];
    __syncthreads();
    if (tid < NG_ * 3) {
        int g = tid / 3, dd = tid % 3;
        float sum = 0.f; int cnt = 0;
        for (int n = 0; n < N_NODES; ++n) {
            if (bl[n] == g) { sum += cl[n * 3 + dd]; cnt++; }
        }
        meanv[tid] = sum / (float)(cnt > 0 ? cnt : 1);
    }
    __syncthreads();
    int g = bl[tid];
    #pragma unroll
    for (int dd = 0; dd < 3; ++dd) {
        float val = cl[tid * 3 + dd] - meanv[g * 3 + dd];
        coords_ws[tid * 3 + dd]  = val;
        coords_out[tid * 3 + dd] = val;
    }
}

// ---------------- fused: last-wins map build (blocks 0..1023) + weight packing (blocks 1024..)
__device__ __forceinline__ void pack_one(
    const float* __restrict__ W, unsigned short* __restrict__ out, int nkb, int idx)
{
    int l = idx & 63;
    int kb = (idx >> 6) % nkb;
    int mtg = idx / (64 * nkb);
    int m = mtg * 16 + (l & 15);
    int k0 = kb * 32 + (l >> 4) * 8;
    bf16x8 pack;
    #pragma unroll
    for (int i = 0; i < 8; ++i) pack[i] = (short)f2bf(W[(size_t)(k0 + i) * SD_ + m]);
    *(bf16x8*)(out + (size_t)idx * 8) = pack;
}

__global__ __launch_bounds__(256) void build_and_pack(
    const int* __restrict__ ei, int* __restrict__ m,
    const float* __restrict__ W_bm, const float* __restrict__ W_b0,
    unsigned short* __restrict__ WfA_bm, unsigned short* __restrict__ WfA_b0)
{
    int bid = blockIdx.x;
    int tid = threadIdx.x;
    if (bid < NE_ / 256) {
        int k = bid * 256 + tid;
        int j = ei[k], i = ei[NE_ + k];
        atomicMax(&m[j * N_NODES + i], k);
    } else {
        int idx = (bid - NE_ / 256) * 256 + tid;   // 0..12287
        if (idx < 4096)  pack_one(W_bm, WfA_bm, 4, idx);
        else             pack_one(W_b0, WfA_b0, 8, idx - 4096);
    }
}

// ---------------- R7: per-edge prep — kills the ei->emap->e dependent chain in edge_mfma.
// k12[k] = {k1, k2, j, i}; dsq[k] = |ci - cj|^2. Latency-tolerant (no barriers, 1024 blocks).
__global__ __launch_bounds__(256) void edge_prep(
    const int* __restrict__ ei, const int* __restrict__ emap, const float* __restrict__ coords,
    int4* __restrict__ k12, float* __restrict__ dsq)
{
    int k = blockIdx.x * 256 + threadIdx.x;
    int j = ei[k], i = ei[NE_ + k];
    int k1 = emap[j * N_NODES + i];
    int k2 = emap[i * N_NODES + j];
    float dx = coords[i * 3 + 0] - coords[j * 3 + 0];
    float dy = coords[i * 3 + 1] - coords[j * 3 + 1];
    float dz = coords[i * 3 + 2] - coords[j * 3 + 2];
    dsq[k] = dx * dx + dy * dy + dz * dz;
    k12[k] = make_int4(k1, k2, j, i);
}

// ---------------- Fused edge pipeline, MFMA version (R4 structure + R7 short gather chain)
// Block = 64 edges, 4 waves. Wave w owns output cols [w*64, w*64+64).
__global__ __launch_bounds__(256) void edge_mfma(
    const float* __restrict__ e, const int4* __restrict__ k12, const float* __restrict__ dsq,
    const float* __restrict__ zrow, const unsigned short* __restrict__ s2b,
    const unsigned short* __restrict__ WfA_bm, const unsigned short* __restrict__ WfA_b0,
    const float* __restrict__ W_b1,
    const float* __restrict__ b_bm, const float* __restrict__ W_b0_last,
    const float* __restrict__ b_b0, const float* __restrict__ b_b1,
    float* __restrict__ bonds_out)
{
    __shared__ __align__(16) char smem0[64 * 128 * 2];   // esym (16KB)  UNION  bonds_part [4][64][5] f32
    __shared__ __align__(16) unsigned short fd_lds[64 * 256]; // 32KB, granule-swizzled [edge][c16^(edge&7)]
    __shared__ unsigned short wb1t[NB_ * 256];           // 2.5KB bf16, [b][m]
    __shared__ float dw[64];
    __shared__ int li_s[64], lj_s[64];

    unsigned short* esym_lds  = (unsigned short*)smem0;
    float*          bonds_part = (float*)smem0;

    const int tid = threadIdx.x;
    const int blk = blockIdx.x;
    const int l   = tid & 63;
    const int w   = tid >> 6;
    const int eLo = l & 15;
    const int hi  = l >> 4;

    // ---- gather (short chain): coalesced k12 load -> both e-rows issued immediately
    {
        const int eL = l;          // edge-local 0..63
        const int q  = w;          // k-chunk 0..3 (32 k each)
        int4 kk = k12[blk * 64 + eL];          // L2-hot (written by edge_prep)
        int k1 = kk.x, k2 = kk.y;
        const float* r1 = e + (size_t)k1 * ED_;
        const float* r2 = (k2 >= 0) ? (e + (size_t)k2 * ED_) : zrow;  // select, no branch
        const float4* p1 = (const float4*)(r1 + q * 32);
        const float4* p2 = (const float4*)(r2 + q * 32);
        float4 va[8], vb[8];
        #pragma unroll
        for (int t = 0; t < 8; ++t) va[t] = p1[t];
        #pragma unroll
        for (int t = 0; t < 8; ++t) vb[t] = p2[t];

        if (w == 0) {
            li_s[eL] = kk.w;   // i
            lj_s[eL] = kk.z;   // j
            dw[eL]   = dsq[blk * 64 + eL];
        }

        #pragma unroll
        for (int t = 0; t < 8; ++t) {
            va[t].x += vb[t].x; va[t].y += vb[t].y;
            va[t].z += vb[t].z; va[t].w += vb[t].w;
        }
        int ntB = eL >> 4, eLoB = eL & 15;
        #pragma unroll
        for (int h2 = 0; h2 < 4; ++h2) {
            float4 x0 = va[h2 * 2], x1 = va[h2 * 2 + 1];
            uint4 c;
            c.x = cvt_pk_bf16(0.5f * x0.x, 0.5f * x0.y);
            c.y = cvt_pk_bf16(0.5f * x0.z, 0.5f * x0.w);
            c.z = cvt_pk_bf16(0.5f * x1.x, 0.5f * x1.y);
            c.w = cvt_pk_bf16(0.5f * x1.z, 0.5f * x1.w);
            int chunk = (ntB * 4 + q) * 64 + h2 * 16 + eLoB;   // lane-linear: 2-way max
            *(uint4*)(&esym_lds[chunk * 8]) = c;
        }
    }

    // ---- stage W_b1^T (bf16) into LDS
    {
        #pragma unroll
        for (int b = 0; b < NB_; ++b)
            wb1t[b * 256 + tid] = f2bf(W_b1[(size_t)tid * NB_ + b]);
    }

    // prefetch GEMM1 kb=0 A-frags (independent of LDS; hides L2 latency under barrier)
    bf16x8 a1p[4];
    #pragma unroll
    for (int mt = 0; mt < 4; ++mt)
        a1p[mt] = *(const bf16x8*)(WfA_bm + ((size_t)(((w * 4 + mt) * 4 + 0) * 64 + l) * 8));

    __syncthreads();   // bar1: esym + meta + wb1t ready

    // ---- GEMM1': K=128 (4 k-steps)
    f32x4 acc[4][4];
    #pragma unroll
    for (int mt = 0; mt < 4; ++mt)
        #pragma unroll
        for (int nt = 0; nt < 4; ++nt) acc[mt][nt] = (f32x4){0.f, 0.f, 0.f, 0.f};

    #pragma unroll
    for (int kb = 0; kb < 4; ++kb) {
        bf16x8 af[4], bfg[4];
        #pragma unroll
        for (int mt = 0; mt < 4; ++mt)
            af[mt] = (kb == 0) ? a1p[mt]
                   : *(const bf16x8*)(WfA_bm + ((size_t)(((w * 4 + mt) * 4 + kb) * 64 + l) * 8));
        #pragma unroll
        for (int nt = 0; nt < 4; ++nt)
            bfg[nt] = *(const bf16x8*)(&esym_lds[(size_t)((nt * 4 + kb) * 64 + l) * 8]);
        __builtin_amdgcn_s_setprio(1);
        #pragma unroll
        for (int mt = 0; mt < 4; ++mt)
            #pragma unroll
            for (int nt = 0; nt < 4; ++nt)
                acc[mt][nt] = __builtin_amdgcn_mfma_f32_16x16x32_bf16(af[mt], bfg[nt], acc[mt][nt], 0, 0, 0);
        __builtin_amdgcn_s_setprio(0);
    }

    // prefetch GEMM2 kb=0 A-frags before the epilogue (T14 issue-early)
    bf16x8 a2p[4];
    #pragma unroll
    for (int mt = 0; mt < 4; ++mt)
        a2p[mt] = *(const bf16x8*)(WfA_b0 + ((size_t)(((w * 4 + mt) * 8 + 0) * 64 + l) * 8));

    // ---- epilogue 1: f = acc + s_i + s_j + b_bm -> swizzled fd (bf16)
    #pragma unroll
    for (int mt = 0; mt < 4; ++mt) {
        int m0 = w * 64 + mt * 16 + hi * 4;
        float4 bb = *(const float4*)(b_bm + m0);
        #pragma unroll
        for (int nt = 0; nt < 4; ++nt) {
            int edge = nt * 16 + eLo;
            int ni = li_s[edge], nj = lj_s[edge];
            ushort4 si = *(const ushort4*)(s2b + (size_t)ni * SD_ + m0);
            ushort4 sj = *(const ushort4*)(s2b + (size_t)nj * SD_ + m0);
            f32x4 r = acc[mt][nt];
            float f0 = r[0] + bf2f(si.x) + bf2f(sj.x) + bb.x;
            float f1 = r[1] + bf2f(si.y) + bf2f(sj.y) + bb.y;
            float f2 = r[2] + bf2f(si.z) + bf2f(sj.z) + bb.z;
            float f3 = r[3] + bf2f(si.w) + bf2f(sj.w) + bb.w;
            uint2 pk;
            pk.x = cvt_pk_bf16(f0, f1);
            pk.y = cvt_pk_bf16(f2, f3);
            int c16 = m0 >> 3;                       // 16B granule index 0..31
            int byteo = (edge << 9) + ((c16 ^ (edge & 7)) << 4) + ((m0 & 7) << 1);
            *(uint2*)((char*)fd_lds + byteo) = pk;
        }
    }
    __syncthreads();   // bar2: fd ready

    // ---- GEMM2': K=256 (8 k-steps); init = b_b0 + d * W_b0[row 256]
    #pragma unroll
    for (int mt = 0; mt < 4; ++mt) {
        int m0 = w * 64 + mt * 16 + hi * 4;
        float4 b0 = *(const float4*)(b_b0 + m0);
        float4 w2 = *(const float4*)(W_b0_last + m0);
        #pragma unroll
        for (int nt = 0; nt < 4; ++nt) {
            float dd = dw[nt * 16 + eLo];
            acc[mt][nt] = (f32x4){fmaf(dd, w2.x, b0.x), fmaf(dd, w2.y, b0.y),
                                  fmaf(dd, w2.z, b0.z), fmaf(dd, w2.w, b0.w)};
        }
    }
    #pragma unroll
    for (int kb = 0; kb < 8; ++kb) {
        bf16x8 af[4], bfg[4];
        #pragma unroll
        for (int mt = 0; mt < 4; ++mt)
            af[mt] = (kb == 0) ? a2p[mt]
                   : *(const bf16x8*)(WfA_b0 + ((size_t)(((w * 4 + mt) * 8 + kb) * 64 + l) * 8));
        #pragma unroll
        for (int nt = 0; nt < 4; ++nt) {
            int edge = nt * 16 + eLo;
            int c16 = (kb << 2) + hi;
            int byteo = (edge << 9) + ((c16 ^ (edge & 7)) << 4);
            bfg[nt] = *(const bf16x8*)((const char*)fd_lds + byteo);
        }
        __builtin_amdgcn_s_setprio(1);
        #pragma unroll
        for (int mt = 0; mt < 4; ++mt)
            #pragma unroll
            for (int nt = 0; nt < 4; ++nt)
                acc[mt][nt] = __builtin_amdgcn_mfma_f32_16x16x32_bf16(af[mt], bfg[nt], acc[mt][nt], 0, 0, 0);
        __builtin_amdgcn_s_setprio(0);
    }

    // ---- bonds: h = silu(pre) fp32, dot with W_b1 (bf16), reduce over m
    float pb[4][NB_];
    #pragma unroll
    for (int nt = 0; nt < 4; ++nt)
        #pragma unroll
        for (int b = 0; b < NB_; ++b) pb[nt][b] = 0.f;
    #pragma unroll
    for (int mt = 0; mt < 4; ++mt) {
        int m0 = w * 64 + mt * 16 + hi * 4;
        ushort4 wv[NB_];
        #pragma unroll
        for (int b = 0; b < NB_; ++b)
            wv[b] = *(const ushort4*)(wb1t + b * 256 + m0);
        #pragma unroll
        for (int nt = 0; nt < 4; ++nt) {
            f32x4 r = acc[mt][nt];
            float h0 = silu_fast(r[0]);
            float h1 = silu_fast(r[1]);
            float h2 = silu_fast(r[2]);
            float h3 = silu_fast(r[3]);
            #pragma unroll
            for (int b = 0; b < NB_; ++b) {
                float t = fmaf(h0, bf2f(wv[b].x), fmaf(h1, bf2f(wv[b].y),
                          fmaf(h2, bf2f(wv[b].z), h3 * bf2f(wv[b].w))));
                pb[nt][b] += t;
            }
        }
    }
    // reduce over hi groups (lanes l, l^16, l^32, l^48 share the same edge column)
    #pragma unroll
    for (int off = 16; off <= 32; off <<= 1)
        #pragma unroll
        for (int nt = 0; nt < 4; ++nt)
            #pragma unroll
            for (int b = 0; b < NB_; ++b)
                pb[nt][b] += __shfl_xor(pb[nt][b], off);
    if (hi == 0) {
        #pragma unroll
        for (int nt = 0; nt < 4; ++nt)
            #pragma unroll
            for (int b = 0; b < NB_; ++b)
                bonds_part[(size_t)(w * 64 + nt * 16 + eLo) * NB_ + b] = pb[nt][b];
    }
    __syncthreads();   // bar3

    // 320 (edge,b) pairs, 256 threads -> strided loop
    for (int idx = tid; idx < 64 * NB_; idx += 256) {
        int edge = idx / NB_, b = idx % NB_;
        float s4 = bonds_part[(size_t)(0 * 64 + edge) * NB_ + b]
                 + bonds_part[(size_t)(1 * 64 + edge) * NB_ + b]
                 + bonds_part[(size_t)(2 * 64 + edge) * NB_ + b]
                 + bonds_part[(size_t)(3 * 64 + edge) * NB_ + b];
        bonds_out[(size_t)(blk * 64 + edge) * NB_ + b] = s4 + b_b1[b];
    }
}

extern "C" void kernel_launch(void* const* d_in, const int* in_sizes, int n_in,
                              void* d_out, int out_size, void* d_ws, size_t ws_size,
                              hipStream_t stream)
{
    const float* s    = (const float*)d_in[0];
    const float* v    = (const float*)d_in[1];
    const float* p    = (const float*)d_in[2];
    const float* e    = (const float*)d_in[3];
    const int*   batch= (const int*)d_in[4];
    const int*   ei   = (const int*)d_in[5];
    const float* W_sm = (const float*)d_in[6];
    const float* b_sm = (const float*)d_in[7];
    const float* W_bm = (const float*)d_in[8];
    const float* b_bm = (const float*)d_in[9];
    const float* W_b0 = (const float*)d_in[10];
    const float* b_b0 = (const float*)d_in[11];
    const float* W_b1 = (const float*)d_in[12];
    const float* b_b1 = (const float*)d_in[13];
    const float* W_c  = (const float*)d_in[14];
    const float* W_a  = (const float*)d_in[15];
    const float* b_a  = (const float*)d_in[16];

    float* out = (float*)d_out;
    float* coords_out = out;                       // 512*3
    float* atoms_out  = out + 1536;                // 512*16
    float* bonds_out  = out + 1536 + 8192;         // 262144*5

    char* ws = (char*)d_ws;
    int*            emap    = (int*)ws;                                  // @0,        1 MB
    unsigned short* s2b     = (unsigned short*)(ws + 0x100000);          // @1MB,    256 KB
    unsigned short* WfA_bm  = (unsigned short*)(ws + 0x140000);          // @1.25MB,  64 KB
    unsigned short* WfA_b0  = (unsigned short*)(ws + 0x150000);          // @1.31MB, 128 KB
    float*          cpred   = (float*)(ws + 0x170000);                   //            6 KB
    float*          coords  = (float*)(ws + 0x172000);                   //            6 KB
    float*          zrow    = (float*)(ws + 0x174000);                   //          512 B
    int4*           k12     = (int4*)(ws + 0x180000);                    //            4 MB
    float*          dsq     = (float*)(ws + 0x580000);                   //            1 MB

    hipMemsetAsync(emap, 0xFF, N_NODES * N_NODES * sizeof(int), stream); // emap = -1
    hipMemsetAsync(zrow, 0, ED_ * sizeof(float), stream);                // zero e-row

    build_and_pack<<<NE_ / 256 + 48, 256, 0, stream>>>(ei, emap, W_bm, W_b0, WfA_bm, WfA_b0);
    node_kernel8<<<N_NODES / 8, 256, 0, stream>>>(s, v, p, W_sm, b_sm, W_a, b_a, W_c,
                                                  s2b, cpred, atoms_out);
    center_kernel<<<1, 512, 0, stream>>>(cpred, batch, coords, coords_out);
    edge_prep<<<NE_ / 256, 256, 0, stream>>>(ei, emap, coords, k12, dsq);

    edge_mfma<<<NE_ / 64, 256, 0, stream>>>(e, k12, dsq, zrow, s2b,
                                            WfA_bm, WfA_b0, W_b1,
                                            b_bm, W_b0 + 256 * SD_, b_b0, b_b1,
                                            bonds_out);
}

// Round 8
// 222.279 us; speedup vs baseline: 1.4031x; 1.0878x over previous
//
#include <hip/hip_runtime.h>
#include <math.h>

#define N_NODES 512
#define SD_ 256
#define VD_ 128
#define ED_ 128
#define NE_ 262144
#define NG_ 16
#define NA_ 16
#define NB_ 5

typedef __attribute__((ext_vector_type(8))) short bf16x8;
typedef __attribute__((ext_vector_type(4))) float f32x4;

__device__ __forceinline__ float silu_f(float x) { return x / (1.0f + expf(-x)); }
__device__ __forceinline__ float silu_fast(float x) {
    return x * __builtin_amdgcn_rcpf(1.0f + __builtin_amdgcn_exp2f(x * -1.44269504f));
}
__device__ __forceinline__ unsigned short f2bf(float x) {
    unsigned int u = __float_as_uint(x);
    return (unsigned short)((u + 0x7fffu + ((u >> 16) & 1u)) >> 16);
}
__device__ __forceinline__ float bf2f(unsigned short h) {
    return __uint_as_float(((unsigned int)h) << 16);
}
__device__ __forceinline__ unsigned int cvt_pk_bf16(float lo, float hi) {
    unsigned int r;
    asm("v_cvt_pk_bf16_f32 %0, %1, %2" : "=v"(r) : "v"(lo), "v"(hi));
    return r;
}

// ---------------- Node phase: 8 nodes per block (W_sm read amortized 8x)
__global__ __launch_bounds__(256) void node_kernel8(
    const float* __restrict__ s, const float* __restrict__ v, const float* __restrict__ p,
    const float* __restrict__ W_sm, const float* __restrict__ b_sm,
    const float* __restrict__ W_a, const float* __restrict__ b_a,
    const float* __restrict__ W_c,
    unsigned short* __restrict__ s2b, float* __restrict__ cpred, float* __restrict__ atoms_out)
{
    const int n0  = blockIdx.x * 8;
    const int tid = threadIdx.x;
    __shared__ float srow[8][SD_];
    __shared__ float s2row[8][SD_];
    #pragma unroll
    for (int n = 0; n < 8; ++n) srow[n][tid] = s[(size_t)(n0 + n) * SD_ + tid];
    __syncthreads();
    float acc[8];
    {
        float bb = b_sm[tid];
        #pragma unroll
        for (int n = 0; n < 8; ++n) acc[n] = bb;
    }
    #pragma unroll 4
    for (int c = 0; c < SD_; ++c) {
        float wv = W_sm[(size_t)c * SD_ + tid];
        #pragma unroll
        for (int n = 0; n < 8; ++n) acc[n] = fmaf(srow[n][c], wv, acc[n]);
    }
    #pragma unroll
    for (int n = 0; n < 8; ++n) {
        float sv = silu_f(acc[n]);
        s2b[(size_t)(n0 + n) * SD_ + tid] = f2bf(sv);
        s2row[n][tid] = sv;
    }
    __syncthreads();
    if (tid < 128) {
        int n = tid >> 4, a = tid & 15;
        float x = b_a[a];
        #pragma unroll 8
        for (int c = 0; c < SD_; ++c) x = fmaf(s2row[n][c], W_a[(size_t)c * NA_ + a], x);
        atoms_out[(size_t)(n0 + n) * NA_ + a] = x;
    } else if (tid < 152) {
        int t = tid - 128;
        int n = t / 3, dd = t % 3;
        float x = p[(n0 + n) * 3 + dd];
        const float* vr = v + (size_t)((n0 + n) * 3 + dd) * VD_;
        #pragma unroll 8
        for (int c = 0; c < VD_; ++c) x = fmaf(vr[c], W_c[c], x);
        cpred[(n0 + n) * 3 + dd] = x;
    }
}

// ---------------- Per-graph mean centering (deterministic serial segment sums)
__global__ __launch_bounds__(512) void center_kernel(
    const float* __restrict__ cpred, const int* __restrict__ batch,
    float* __restrict__ coords_ws, float* __restrict__ coords_out)
{
    __shared__ float cl[N_NODES * 3];
    __shared__ int   bl[N_NODES];
    __shared__ float meanv[NG_ * 3];
    const int tid = threadIdx.x;
    bl[tid] = batch[tid];
    #pragma unroll
    for (int dd = 0; dd < 3; ++dd) cl[tid * 3 + dd] = cpred[tid * 3 + dd];
    __syncthreads();
    if (tid < NG_ * 3) {
        int g = tid / 3, dd = tid % 3;
        float sum = 0.f; int cnt = 0;
        for (int n = 0; n < N_NODES; ++n) {
            if (bl[n] == g) { sum += cl[n * 3 + dd]; cnt++; }
        }
        meanv[tid] = sum / (float)(cnt > 0 ? cnt : 1);
    }
    __syncthreads();
    int g = bl[tid];
    #pragma unroll
    for (int dd = 0; dd < 3; ++dd) {
        float val = cl[tid * 3 + dd] - meanv[g * 3 + dd];
        coords_ws[tid * 3 + dd]  = val;
        coords_out[tid * 3 + dd] = val;
    }
}

// ---------------- fused: last-wins map build (blocks 0..1023) + weight packing (blocks 1024..)
__device__ __forceinline__ void pack_one(
    const float* __restrict__ W, unsigned short* __restrict__ out, int nkb, int idx)
{
    int l = idx & 63;
    int kb = (idx >> 6) % nkb;
    int mtg = idx / (64 * nkb);
    int m = mtg * 16 + (l & 15);
    int k0 = kb * 32 + (l >> 4) * 8;
    bf16x8 pack;
    #pragma unroll
    for (int i = 0; i < 8; ++i) pack[i] = (short)f2bf(W[(size_t)(k0 + i) * SD_ + m]);
    *(bf16x8*)(out + (size_t)idx * 8) = pack;
}

__global__ __launch_bounds__(256) void build_and_pack(
    const int* __restrict__ ei, int* __restrict__ m,
    const float* __restrict__ W_bm, const float* __restrict__ W_b0,
    unsigned short* __restrict__ WfA_bm, unsigned short* __restrict__ WfA_b0)
{
    int bid = blockIdx.x;
    int tid = threadIdx.x;
    if (bid < NE_ / 256) {
        int k = bid * 256 + tid;
        int j = ei[k], i = ei[NE_ + k];
        atomicMax(&m[j * N_NODES + i], k);
    } else {
        int idx = (bid - NE_ / 256) * 256 + tid;   // 0..12287
        if (idx < 4096)  pack_one(W_bm, WfA_bm, 4, idx);
        else             pack_one(W_b0, WfA_b0, 8, idx - 4096);
    }
}

// ---------------- Fused edge pipeline, MFMA version
// R8: 512 threads / 8 waves per block; wave w owns a 32-col strip (acc 2x4 tiles).
// Same algorithm/swizzles/barriers as R4; per-wave VGPR footprint ~halved so
// 3 blocks/CU = 24 waves/CU (2x R4's 12) fit under the 512-VGPR/SIMD budget.
__global__ __launch_bounds__(512) void edge_mfma(
    const float* __restrict__ e, const int* __restrict__ ei, const int* __restrict__ emap,
    const float* __restrict__ coords, const unsigned short* __restrict__ s2b,
    const unsigned short* __restrict__ WfA_bm, const unsigned short* __restrict__ WfA_b0,
    const float* __restrict__ W_b1,
    const float* __restrict__ b_bm, const float* __restrict__ W_b0_last,
    const float* __restrict__ b_b0, const float* __restrict__ b_b1,
    float* __restrict__ bonds_out)
{
    __shared__ __align__(16) char smem0[64 * 128 * 2];   // esym (16KB) UNION bonds_part [8][64][5] f32 (10KB)
    __shared__ __align__(16) unsigned short fd_lds[64 * 256]; // 32KB, granule-swizzled [edge][c16^(edge&7)]
    __shared__ unsigned short wb1t[NB_ * 256];           // 2.5KB bf16, [b][m]
    __shared__ float dw[64];
    __shared__ int li_s[64], lj_s[64];

    unsigned short* esym_lds  = (unsigned short*)smem0;
    float*          bonds_part = (float*)smem0;

    const int tid = threadIdx.x;
    const int blk = blockIdx.x;
    const int l   = tid & 63;
    const int w   = tid >> 6;       // 0..7
    const int eLo = l & 15;
    const int hi  = l >> 4;

    // ---- meta: one thread per edge
    if (tid < 64) {
        int ge = blk * 64 + tid;
        int j = ei[ge], i2 = ei[NE_ + ge];
        li_s[tid] = i2; lj_s[tid] = j;
        float dx = coords[i2 * 3 + 0] - coords[j * 3 + 0];
        float dy = coords[i2 * 3 + 1] - coords[j * 3 + 1];
        float dz = coords[i2 * 3 + 2] - coords[j * 3 + 2];
        dw[tid] = dx * dx + dy * dy + dz * dz;
    }

    // ---- gather + symmetrize: 8 threads per edge, 16 floats each
    {
        const int eL = tid >> 3;    // 0..63
        const int q  = tid & 7;     // 16-float chunk (k = q*16 .. q*16+15)
        int ge = blk * 64 + eL;
        int j  = ei[ge], i2 = ei[NE_ + ge];
        int k1 = emap[j * N_NODES + i2];
        int k2 = emap[i2 * N_NODES + j];
        const float4* p1 = (const float4*)(e + (size_t)k1 * ED_ + q * 16);
        float4 va[4];
        #pragma unroll
        for (int t = 0; t < 4; ++t) va[t] = p1[t];
        if (k2 >= 0) {
            const float4* p2 = (const float4*)(e + (size_t)k2 * ED_ + q * 16);
            #pragma unroll
            for (int t = 0; t < 4; ++t) {
                float4 b4 = p2[t];
                va[t].x += b4.x; va[t].y += b4.y; va[t].z += b4.z; va[t].w += b4.w;
            }
        }
        int ntB = eL >> 4, eLoB = eL & 15, q4 = q >> 1;
        #pragma unroll
        for (int t = 0; t < 2; ++t) {
            float4 x0 = va[t * 2], x1 = va[t * 2 + 1];
            uint4 c;
            c.x = cvt_pk_bf16(0.5f * x0.x, 0.5f * x0.y);
            c.y = cvt_pk_bf16(0.5f * x0.z, 0.5f * x0.w);
            c.z = cvt_pk_bf16(0.5f * x1.x, 0.5f * x1.y);
            c.w = cvt_pk_bf16(0.5f * x1.z, 0.5f * x1.w);
            int h2 = (q & 1) * 2 + t;           // 8-k sub-block within the 32-k block
            int chunk = (ntB * 4 + q4) * 64 + h2 * 16 + eLoB;
            *(uint4*)(&esym_lds[chunk * 8]) = c;
        }
    }

    // ---- stage W_b1^T (bf16) into LDS
    if (tid < 256) {
        #pragma unroll
        for (int b = 0; b < NB_; ++b)
            wb1t[b * 256 + tid] = f2bf(W_b1[(size_t)tid * NB_ + b]);
    }

    // prefetch GEMM1 kb=0 A-frags (wave strip: mtg = w*2+mt)
    bf16x8 a1p[2];
    #pragma unroll
    for (int mt = 0; mt < 2; ++mt)
        a1p[mt] = *(const bf16x8*)(WfA_bm + ((size_t)(((w * 2 + mt) * 4 + 0) * 64 + l) * 8));

    __syncthreads();   // bar1: esym + meta + wb1t ready

    // ---- GEMM1': K=128 (4 k-steps), wave computes 32 cols x 64 edges
    f32x4 acc[2][4];
    #pragma unroll
    for (int mt = 0; mt < 2; ++mt)
        #pragma unroll
        for (int nt = 0; nt < 4; ++nt) acc[mt][nt] = (f32x4){0.f, 0.f, 0.f, 0.f};

    #pragma unroll
    for (int kb = 0; kb < 4; ++kb) {
        bf16x8 af[2], bfg[4];
        #pragma unroll
        for (int mt = 0; mt < 2; ++mt)
            af[mt] = (kb == 0) ? a1p[mt]
                   : *(const bf16x8*)(WfA_bm + ((size_t)(((w * 2 + mt) * 4 + kb) * 64 + l) * 8));
        #pragma unroll
        for (int nt = 0; nt < 4; ++nt)
            bfg[nt] = *(const bf16x8*)(&esym_lds[(size_t)((nt * 4 + kb) * 64 + l) * 8]);
        __builtin_amdgcn_s_setprio(1);
        #pragma unroll
        for (int mt = 0; mt < 2; ++mt)
            #pragma unroll
            for (int nt = 0; nt < 4; ++nt)
                acc[mt][nt] = __builtin_amdgcn_mfma_f32_16x16x32_bf16(af[mt], bfg[nt], acc[mt][nt], 0, 0, 0);
        __builtin_amdgcn_s_setprio(0);
    }

    // prefetch GEMM2 kb=0 A-frags
    bf16x8 a2p[2];
    #pragma unroll
    for (int mt = 0; mt < 2; ++mt)
        a2p[mt] = *(const bf16x8*)(WfA_b0 + ((size_t)(((w * 2 + mt) * 8 + 0) * 64 + l) * 8));

    // ---- epilogue 1: f = acc + s_i + s_j + b_bm -> swizzled fd (bf16)
    #pragma unroll
    for (int mt = 0; mt < 2; ++mt) {
        int m0 = w * 32 + mt * 16 + hi * 4;
        float4 bb = *(const float4*)(b_bm + m0);
        #pragma unroll
        for (int nt = 0; nt < 4; ++nt) {
            int edge = nt * 16 + eLo;
            int ni = li_s[edge], nj = lj_s[edge];
            ushort4 si = *(const ushort4*)(s2b + (size_t)ni * SD_ + m0);
            ushort4 sj = *(const ushort4*)(s2b + (size_t)nj * SD_ + m0);
            f32x4 r = acc[mt][nt];
            float f0 = r[0] + bf2f(si.x) + bf2f(sj.x) + bb.x;
            float f1 = r[1] + bf2f(si.y) + bf2f(sj.y) + bb.y;
            float f2 = r[2] + bf2f(si.z) + bf2f(sj.z) + bb.z;
            float f3 = r[3] + bf2f(si.w) + bf2f(sj.w) + bb.w;
            uint2 pk;
            pk.x = cvt_pk_bf16(f0, f1);
            pk.y = cvt_pk_bf16(f2, f3);
            int c16 = m0 >> 3;                       // 16B granule index 0..31
            int byteo = (edge << 9) + ((c16 ^ (edge & 7)) << 4) + ((m0 & 7) << 1);
            *(uint2*)((char*)fd_lds + byteo) = pk;
        }
    }
    __syncthreads();   // bar2: fd ready

    // ---- GEMM2': K=256 (8 k-steps); init = b_b0 + d * W_b0[row 256]
    #pragma unroll
    for (int mt = 0; mt < 2; ++mt) {
        int m0 = w * 32 + mt * 16 + hi * 4;
        float4 b0 = *(const float4*)(b_b0 + m0);
        float4 w2 = *(const float4*)(W_b0_last + m0);
        #pragma unroll
        for (int nt = 0; nt < 4; ++nt) {
            float dd = dw[nt * 16 + eLo];
            acc[mt][nt] = (f32x4){fmaf(dd, w2.x, b0.x), fmaf(dd, w2.y, b0.y),
                                  fmaf(dd, w2.z, b0.z), fmaf(dd, w2.w, b0.w)};
        }
    }
    #pragma unroll
    for (int kb = 0; kb < 8; ++kb) {
        bf16x8 af[2], bfg[4];
        #pragma unroll
        for (int mt = 0; mt < 2; ++mt)
            af[mt] = (kb == 0) ? a2p[mt]
                   : *(const bf16x8*)(WfA_b0 + ((size_t)(((w * 2 + mt) * 8 + kb) * 64 + l) * 8));
        #pragma unroll
        for (int nt = 0; nt < 4; ++nt) {
            int edge = nt * 16 + eLo;
            int c16 = (kb << 2) + hi;
            int byteo = (edge << 9) + ((c16 ^ (edge & 7)) << 4);
            bfg[nt] = *(const bf16x8*)((const char*)fd_lds + byteo);
        }
        __builtin_amdgcn_s_setprio(1);
        #pragma unroll
        for (int mt = 0; mt < 2; ++mt)
            #pragma unroll
            for (int nt = 0; nt < 4; ++nt)
                acc[mt][nt] = __builtin_amdgcn_mfma_f32_16x16x32_bf16(af[mt], bfg[nt], acc[mt][nt], 0, 0, 0);
        __builtin_amdgcn_s_setprio(0);
    }

    // ---- bonds: h = silu(pre) fp32, dot with W_b1 (bf16), reduce over m (strip = 32 cols)
    float pb[4][NB_];
    #pragma unroll
    for (int nt = 0; nt < 4; ++nt)
        #pragma unroll
        for (int b = 0; b < NB_; ++b) pb[nt][b] = 0.f;
    #pragma unroll
    for (int mt = 0; mt < 2; ++mt) {
        int m0 = w * 32 + mt * 16 + hi * 4;
        ushort4 wv[NB_];
        #pragma unroll
        for (int b = 0; b < NB_; ++b)
            wv[b] = *(const ushort4*)(wb1t + b * 256 + m0);
        #pragma unroll
        for (int nt = 0; nt < 4; ++nt) {
            f32x4 r = acc[mt][nt];
            float h0 = silu_fast(r[0]);
            float h1 = silu_fast(r[1]);
            float h2 = silu_fast(r[2]);
            float h3 = silu_fast(r[3]);
            #pragma unroll
            for (int b = 0; b < NB_; ++b) {
                float t = fmaf(h0, bf2f(wv[b].x), fmaf(h1, bf2f(wv[b].y),
                          fmaf(h2, bf2f(wv[b].z), h3 * bf2f(wv[b].w))));
                pb[nt][b] += t;
            }
        }
    }
    // reduce over hi groups (lanes l, l^16, l^32, l^48 share the same edge column)
    #pragma unroll
    for (int off = 16; off <= 32; off <<= 1)
        #pragma unroll
        for (int nt = 0; nt < 4; ++nt)
            #pragma unroll
            for (int b = 0; b < NB_; ++b)
                pb[nt][b] += __shfl_xor(pb[nt][b], off);
    if (hi == 0) {
        #pragma unroll
        for (int nt = 0; nt < 4; ++nt)
            #pragma unroll
            for (int b = 0; b < NB_; ++b)
                bonds_part[(size_t)(w * 64 + nt * 16 + eLo) * NB_ + b] = pb[nt][b];
    }
    __syncthreads();   // bar3

    // 320 (edge,b) pairs, 512 threads
    for (int idx = tid; idx < 64 * NB_; idx += 512) {
        int edge = idx / NB_, b = idx % NB_;
        float s8 = 0.f;
        #pragma unroll
        for (int p = 0; p < 8; ++p)
            s8 += bonds_part[(size_t)(p * 64 + edge) * NB_ + b];
        bonds_out[(size_t)(blk * 64 + edge) * NB_ + b] = s8 + b_b1[b];
    }
}

extern "C" void kernel_launch(void* const* d_in, const int* in_sizes, int n_in,
                              void* d_out, int out_size, void* d_ws, size_t ws_size,
                              hipStream_t stream)
{
    const float* s    = (const float*)d_in[0];
    const float* v    = (const float*)d_in[1];
    const float* p    = (const float*)d_in[2];
    const float* e    = (const float*)d_in[3];
    const int*   batch= (const int*)d_in[4];
    const int*   ei   = (const int*)d_in[5];
    const float* W_sm = (const float*)d_in[6];
    const float* b_sm = (const float*)d_in[7];
    const float* W_bm = (const float*)d_in[8];
    const float* b_bm = (const float*)d_in[9];
    const float* W_b0 = (const float*)d_in[10];
    const float* b_b0 = (const float*)d_in[11];
    const float* W_b1 = (const float*)d_in[12];
    const float* b_b1 = (const float*)d_in[13];
    const float* W_c  = (const float*)d_in[14];
    const float* W_a  = (const float*)d_in[15];
    const float* b_a  = (const float*)d_in[16];

    float* out = (float*)d_out;
    float* coords_out = out;                       // 512*3
    float* atoms_out  = out + 1536;                // 512*16
    float* bonds_out  = out + 1536 + 8192;         // 262144*5

    char* ws = (char*)d_ws;
    int*            emap    = (int*)ws;                                  // @0,        1 MB
    unsigned short* s2b     = (unsigned short*)(ws + 0x100000);          // @1MB,    256 KB
    unsigned short* WfA_bm  = (unsigned short*)(ws + 0x140000);          // @1.25MB,  64 KB
    unsigned short* WfA_b0  = (unsigned short*)(ws + 0x150000);          // @1.31MB, 128 KB
    float*          cpred   = (float*)(ws + 0x170000);                   //            6 KB
    float*          coords  = (float*)(ws + 0x172000);                   //            6 KB

    hipMemsetAsync(emap, 0xFF, N_NODES * N_NODES * sizeof(int), stream); // emap = -1

    build_and_pack<<<NE_ / 256 + 48, 256, 0, stream>>>(ei, emap, W_bm, W_b0, WfA_bm, WfA_b0);
    node_kernel8<<<N_NODES / 8, 256, 0, stream>>>(s, v, p, W_sm, b_sm, W_a, b_a, W_c,
                                                  s2b, cpred, atoms_out);
    center_kernel<<<1, 512, 0, stream>>>(cpred, batch, coords, coords_out);

    edge_mfma<<<NE_ / 64, 512, 0, stream>>>(e, ei, emap, coords, s2b,
                                            WfA_bm, WfA_b0, W_b1,
                                            b_bm, W_b0 + 256 * SD_, b_b0, b_b1,
                                            bonds_out);
}

// Round 9
// 186.383 us; speedup vs baseline: 1.6733x; 1.1926x over previous
//
#include <hip/hip_runtime.h>
#include <math.h>

#define N_NODES 512
#define SD_ 256
#define VD_ 128
#define ED_ 128
#define NE_ 262144
#define NG_ 16
#define NA_ 16
#define NB_ 5
#define MAXP 131328   // N*(N+1)/2 upper bound on distinct unordered pairs

typedef __attribute__((ext_vector_type(8))) short bf16x8;
typedef __attribute__((ext_vector_type(4))) float f32x4;

__device__ __forceinline__ float silu_f(float x) { return x / (1.0f + expf(-x)); }
__device__ __forceinline__ float silu_fast(float x) {
    return x * __builtin_amdgcn_rcpf(1.0f + __builtin_amdgcn_exp2f(x * -1.44269504f));
}
__device__ __forceinline__ unsigned short f2bf(float x) {
    unsigned int u = __float_as_uint(x);
    return (unsigned short)((u + 0x7fffu + ((u >> 16) & 1u)) >> 16);
}
__device__ __forceinline__ float bf2f(unsigned short h) {
    return __uint_as_float(((unsigned int)h) << 16);
}
__device__ __forceinline__ unsigned int cvt_pk_bf16(float lo, float hi) {
    unsigned int r;
    asm("v_cvt_pk_bf16_f32 %0, %1, %2" : "=v"(r) : "v"(lo), "v"(hi));
    return r;
}

// ---------------- Node phase: 8 nodes per block (W_sm read amortized 8x)
__global__ __launch_bounds__(256) void node_kernel8(
    const float* __restrict__ s, const float* __restrict__ v, const float* __restrict__ p,
    const float* __restrict__ W_sm, const float* __restrict__ b_sm,
    const float* __restrict__ W_a, const float* __restrict__ b_a,
    const float* __restrict__ W_c,
    unsigned short* __restrict__ s2b, float* __restrict__ cpred, float* __restrict__ atoms_out)
{
    const int n0  = blockIdx.x * 8;
    const int tid = threadIdx.x;
    __shared__ float srow[8][SD_];
    __shared__ float s2row[8][SD_];
    #pragma unroll
    for (int n = 0; n < 8; ++n) srow[n][tid] = s[(size_t)(n0 + n) * SD_ + tid];
    __syncthreads();
    float acc[8];
    {
        float bb = b_sm[tid];
        #pragma unroll
        for (int n = 0; n < 8; ++n) acc[n] = bb;
    }
    #pragma unroll 4
    for (int c = 0; c < SD_; ++c) {
        float wv = W_sm[(size_t)c * SD_ + tid];
        #pragma unroll
        for (int n = 0; n < 8; ++n) acc[n] = fmaf(srow[n][c], wv, acc[n]);
    }
    #pragma unroll
    for (int n = 0; n < 8; ++n) {
        float sv = silu_f(acc[n]);
        s2b[(size_t)(n0 + n) * SD_ + tid] = f2bf(sv);
        s2row[n][tid] = sv;
    }
    __syncthreads();
    if (tid < 128) {
        int n = tid >> 4, a = tid & 15;
        float x = b_a[a];
        #pragma unroll 8
        for (int c = 0; c < SD_; ++c) x = fmaf(s2row[n][c], W_a[(size_t)c * NA_ + a], x);
        atoms_out[(size_t)(n0 + n) * NA_ + a] = x;
    } else if (tid < 152) {
        int t = tid - 128;
        int n = t / 3, dd = t % 3;
        float x = p[(n0 + n) * 3 + dd];
        const float* vr = v + (size_t)((n0 + n) * 3 + dd) * VD_;
        #pragma unroll 8
        for (int c = 0; c < VD_; ++c) x = fmaf(vr[c], W_c[c], x);
        cpred[(n0 + n) * 3 + dd] = x;
    }
}

// ---------------- Per-graph mean centering (deterministic serial segment sums)
__global__ __launch_bounds__(512) void center_kernel(
    const float* __restrict__ cpred, const int* __restrict__ batch,
    float* __restrict__ coords_ws, float* __restrict__ coords_out)
{
    __shared__ float cl[N_NODES * 3];
    __shared__ int   bl[N_NODES];
    __shared__ float meanv[NG_ * 3];
    const int tid = threadIdx.x;
    bl[tid] = batch[tid];
    #pragma unroll
    for (int dd = 0; dd < 3; ++dd) cl[tid * 3 + dd] = cpred[tid * 3 + dd];
    __syncthreads();
    if (tid < NG_ * 3) {
        int g = tid / 3, dd = tid % 3;
        float sum = 0.f; int cnt = 0;
        for (int n = 0; n < N_NODES; ++n) {
            if (bl[n] == g) { sum += cl[n * 3 + dd]; cnt++; }
        }
        meanv[tid] = sum / (float)(cnt > 0 ? cnt : 1);
    }
    __syncthreads();
    int g = bl[tid];
    #pragma unroll
    for (int dd = 0; dd < 3; ++dd) {
        float val = cl[tid * 3 + dd] - meanv[g * 3 + dd];
        coords_ws[tid * 3 + dd]  = val;
        coords_out[tid * 3 + dd] = val;
    }
}

// ---------------- fused: last-wins map build (blocks 0..1023) + weight packing (blocks 1024..)
__device__ __forceinline__ void pack_one(
    const float* __restrict__ W, unsigned short* __restrict__ out, int nkb, int idx)
{
    int l = idx & 63;
    int kb = (idx >> 6) % nkb;
    int mtg = idx / (64 * nkb);
    int m = mtg * 16 + (l & 15);
    int k0 = kb * 32 + (l >> 4) * 8;
    bf16x8 pack;
    #pragma unroll
    for (int i = 0; i < 8; ++i) pack[i] = (short)f2bf(W[(size_t)(k0 + i) * SD_ + m]);
    *(bf16x8*)(out + (size_t)idx * 8) = pack;
}

__global__ __launch_bounds__(256) void build_and_pack(
    const int* __restrict__ ei, int* __restrict__ m,
    const float* __restrict__ W_bm, const float* __restrict__ W_b0,
    unsigned short* __restrict__ WfA_bm, unsigned short* __restrict__ WfA_b0)
{
    int bid = blockIdx.x;
    int tid = threadIdx.x;
    if (bid < NE_ / 256) {
        int k = bid * 256 + tid;
        int j = ei[k], i = ei[NE_ + k];
        atomicMax(&m[j * N_NODES + i], k);
    } else {
        int idx = (bid - NE_ / 256) * 256 + tid;   // 0..12287
        if (idx < 4096)  pack_one(W_bm, WfA_bm, 4, idx);
        else             pack_one(W_b0, WfA_b0, 8, idx - 4096);
    }
}

// ---------------- R9: compact distinct UNORDERED pairs. bonds depends only on {a,b}
// (e_sym, d, s_i+s_j all symmetric) -> compute once per pair, scatter to edges.
__global__ __launch_bounds__(256) void pair_build(
    const int* __restrict__ emap, int* __restrict__ counter,
    int* __restrict__ pairslot, int4* __restrict__ worklist)
{
    int idx = blockIdx.x * 256 + threadIdx.x;   // 0..262143 = all (a,b) cells
    int a = idx >> 9, b = idx & (N_NODES - 1);
    if (a > b) return;
    int k1 = emap[(a << 9) | b];
    int k2 = emap[(b << 9) | a];
    if (k1 >= 0 || k2 >= 0) {
        int slot = atomicAdd(counter, 1);
        pairslot[(a << 9) | b] = slot;
        pairslot[(b << 9) | a] = slot;
        worklist[slot] = make_int4(a, b, k1, k2);
    }
}

// ---------------- scatter representative bonds to all edges
__global__ __launch_bounds__(256) void bonds_scatter(
    const int* __restrict__ ei, const int* __restrict__ pairslot,
    const float* __restrict__ repval, float* __restrict__ bonds_out)
{
    int k = blockIdx.x * 256 + threadIdx.x;
    int j = ei[k], i = ei[NE_ + k];
    int slot = pairslot[(j << 9) | i];
    const float* rp = repval + (size_t)slot * NB_;
    #pragma unroll
    for (int b = 0; b < NB_; ++b)
        bonds_out[(size_t)k * NB_ + b] = rp[b];
}

// ---------------- Fused edge pipeline over DISTINCT pairs (R8 8-wave strips,
// R4 gather mapping restored). Block = 64 pairs; early-exit past count.
__global__ __launch_bounds__(512) void edge_mfma(
    const float* __restrict__ e, const int4* __restrict__ worklist,
    const int* __restrict__ counter, const float* __restrict__ coords,
    const float* __restrict__ zrow, const unsigned short* __restrict__ s2b,
    const unsigned short* __restrict__ WfA_bm, const unsigned short* __restrict__ WfA_b0,
    const float* __restrict__ W_b1,
    const float* __restrict__ b_bm, const float* __restrict__ W_b0_last,
    const float* __restrict__ b_b0, const float* __restrict__ b_b1,
    float* __restrict__ repval)
{
    const int blk = blockIdx.x;
    const int cnt = counter[0];
    if (blk * 64 >= cnt) return;

    __shared__ __align__(16) char smem0[64 * 128 * 2];   // esym (16KB) UNION bonds_part [8][64][5] (10KB)
    __shared__ __align__(16) unsigned short fd_lds[64 * 256]; // 32KB, swizzled [pair][c16^(pair&7)]
    __shared__ unsigned short wb1t[NB_ * 256];
    __shared__ float dw[64];
    __shared__ int li_s[64], lj_s[64];

    unsigned short* esym_lds   = (unsigned short*)smem0;
    float*          bonds_part = (float*)smem0;

    const int tid = threadIdx.x;
    const int l   = tid & 63;
    const int w   = tid >> 6;       // 0..7
    const int eLo = l & 15;
    const int hi  = l >> 4;

    if (tid < 256) {
        // ---- gather + symmetrize (R4 mapping: eL = l, q = wave 0..3, 32 floats/thread)
        const int eL = l;
        const int q  = w;           // 0..3
        int widx = min(blk * 64 + eL, cnt - 1);   // tail-clamp: duplicate of last pair
        int4 wk = worklist[widx];
        const float* r1 = (wk.z >= 0) ? (e + (size_t)wk.z * ED_) : zrow;
        const float* r2 = (wk.w >= 0) ? (e + (size_t)wk.w * ED_) : zrow;
        const float4* p1 = (const float4*)(r1 + q * 32);
        const float4* p2 = (const float4*)(r2 + q * 32);
        float4 va[8], vb[8];
        #pragma unroll
        for (int t = 0; t < 8; ++t) va[t] = p1[t];
        #pragma unroll
        for (int t = 0; t < 8; ++t) vb[t] = p2[t];
        #pragma unroll
        for (int t = 0; t < 8; ++t) {
            va[t].x += vb[t].x; va[t].y += vb[t].y;
            va[t].z += vb[t].z; va[t].w += vb[t].w;
        }
        int ntB = eL >> 4, eLoB = eL & 15;
        #pragma unroll
        for (int h2 = 0; h2 < 4; ++h2) {
            float4 x0 = va[h2 * 2], x1 = va[h2 * 2 + 1];
            uint4 c;
            c.x = cvt_pk_bf16(0.5f * x0.x, 0.5f * x0.y);
            c.y = cvt_pk_bf16(0.5f * x0.z, 0.5f * x0.w);
            c.z = cvt_pk_bf16(0.5f * x1.x, 0.5f * x1.y);
            c.w = cvt_pk_bf16(0.5f * x1.z, 0.5f * x1.w);
            int chunk = (ntB * 4 + q) * 64 + h2 * 16 + eLoB;   // R4 pattern (low-conflict)
            *(uint4*)(&esym_lds[chunk * 8]) = c;
        }
    } else {
        // ---- waves 4-7: W_b1 staging + per-pair meta
        int t = tid - 256;          // 0..255
        #pragma unroll
        for (int b = 0; b < NB_; ++b)
            wb1t[b * 256 + t] = f2bf(W_b1[(size_t)t * NB_ + b]);
        if (t < 64) {
            int widx = min(blk * 64 + t, cnt - 1);
            int4 wk = worklist[widx];
            li_s[t] = wk.x; lj_s[t] = wk.y;
            float dx = coords[wk.x * 3 + 0] - coords[wk.y * 3 + 0];
            float dy = coords[wk.x * 3 + 1] - coords[wk.y * 3 + 1];
            float dz = coords[wk.x * 3 + 2] - coords[wk.y * 3 + 2];
            dw[t] = dx * dx + dy * dy + dz * dz;
        }
    }

    // prefetch GEMM1 kb=0 A-frags (strip mtg = w*2+mt)
    bf16x8 a1p[2];
    #pragma unroll
    for (int mt = 0; mt < 2; ++mt)
        a1p[mt] = *(const bf16x8*)(WfA_bm + ((size_t)(((w * 2 + mt) * 4 + 0) * 64 + l) * 8));

    __syncthreads();   // bar1: esym + meta + wb1t ready

    // ---- GEMM1': K=128 (4 k-steps), wave computes 32 cols x 64 pairs
    f32x4 acc[2][4];
    #pragma unroll
    for (int mt = 0; mt < 2; ++mt)
        #pragma unroll
        for (int nt = 0; nt < 4; ++nt) acc[mt][nt] = (f32x4){0.f, 0.f, 0.f, 0.f};

    #pragma unroll
    for (int kb = 0; kb < 4; ++kb) {
        bf16x8 af[2], bfg[4];
        #pragma unroll
        for (int mt = 0; mt < 2; ++mt)
            af[mt] = (kb == 0) ? a1p[mt]
                   : *(const bf16x8*)(WfA_bm + ((size_t)(((w * 2 + mt) * 4 + kb) * 64 + l) * 8));
        #pragma unroll
        for (int nt = 0; nt < 4; ++nt)
            bfg[nt] = *(const bf16x8*)(&esym_lds[(size_t)((nt * 4 + kb) * 64 + l) * 8]);
        __builtin_amdgcn_s_setprio(1);
        #pragma unroll
        for (int mt = 0; mt < 2; ++mt)
            #pragma unroll
            for (int nt = 0; nt < 4; ++nt)
                acc[mt][nt] = __builtin_amdgcn_mfma_f32_16x16x32_bf16(af[mt], bfg[nt], acc[mt][nt], 0, 0, 0);
        __builtin_amdgcn_s_setprio(0);
    }

    // prefetch GEMM2 kb=0 A-frags
    bf16x8 a2p[2];
    #pragma unroll
    for (int mt = 0; mt < 2; ++mt)
        a2p[mt] = *(const bf16x8*)(WfA_b0 + ((size_t)(((w * 2 + mt) * 8 + 0) * 64 + l) * 8));

    // ---- epilogue 1: f = acc + s_a + s_b + b_bm -> swizzled fd (bf16)
    #pragma unroll
    for (int mt = 0; mt < 2; ++mt) {
        int m0 = w * 32 + mt * 16 + hi * 4;
        float4 bb = *(const float4*)(b_bm + m0);
        #pragma unroll
        for (int nt = 0; nt < 4; ++nt) {
            int edge = nt * 16 + eLo;
            int ni = li_s[edge], nj = lj_s[edge];
            ushort4 si = *(const ushort4*)(s2b + (size_t)ni * SD_ + m0);
            ushort4 sj = *(const ushort4*)(s2b + (size_t)nj * SD_ + m0);
            f32x4 r = acc[mt][nt];
            float f0 = r[0] + bf2f(si.x) + bf2f(sj.x) + bb.x;
            float f1 = r[1] + bf2f(si.y) + bf2f(sj.y) + bb.y;
            float f2 = r[2] + bf2f(si.z) + bf2f(sj.z) + bb.z;
            float f3 = r[3] + bf2f(si.w) + bf2f(sj.w) + bb.w;
            uint2 pk;
            pk.x = cvt_pk_bf16(f0, f1);
            pk.y = cvt_pk_bf16(f2, f3);
            int c16 = m0 >> 3;
            int byteo = (edge << 9) + ((c16 ^ (edge & 7)) << 4) + ((m0 & 7) << 1);
            *(uint2*)((char*)fd_lds + byteo) = pk;
        }
    }
    __syncthreads();   // bar2: fd ready

    // ---- GEMM2': K=256 (8 k-steps); init = b_b0 + d * W_b0[row 256]
    #pragma unroll
    for (int mt = 0; mt < 2; ++mt) {
        int m0 = w * 32 + mt * 16 + hi * 4;
        float4 b0 = *(const float4*)(b_b0 + m0);
        float4 w2 = *(const float4*)(W_b0_last + m0);
        #pragma unroll
        for (int nt = 0; nt < 4; ++nt) {
            float dd = dw[nt * 16 + eLo];
            acc[mt][nt] = (f32x4){fmaf(dd, w2.x, b0.x), fmaf(dd, w2.y, b0.y),
                                  fmaf(dd, w2.z, b0.z), fmaf(dd, w2.w, b0.w)};
        }
    }
    #pragma unroll
    for (int kb = 0; kb < 8; ++kb) {
        bf16x8 af[2], bfg[4];
        #pragma unroll
        for (int mt = 0; mt < 2; ++mt)
            af[mt] = (kb == 0) ? a2p[mt]
                   : *(const bf16x8*)(WfA_b0 + ((size_t)(((w * 2 + mt) * 8 + kb) * 64 + l) * 8));
        #pragma unroll
        for (int nt = 0; nt < 4; ++nt) {
            int edge = nt * 16 + eLo;
            int c16 = (kb << 2) + hi;
            int byteo = (edge << 9) + ((c16 ^ (edge & 7)) << 4);
            bfg[nt] = *(const bf16x8*)((const char*)fd_lds + byteo);
        }
        __builtin_amdgcn_s_setprio(1);
        #pragma unroll
        for (int mt = 0; mt < 2; ++mt)
            #pragma unroll
            for (int nt = 0; nt < 4; ++nt)
                acc[mt][nt] = __builtin_amdgcn_mfma_f32_16x16x32_bf16(af[mt], bfg[nt], acc[mt][nt], 0, 0, 0);
        __builtin_amdgcn_s_setprio(0);
    }

    // ---- bonds: h = silu(pre) fp32, dot with W_b1 (bf16), reduce over strip cols
    float pb[4][NB_];
    #pragma unroll
    for (int nt = 0; nt < 4; ++nt)
        #pragma unroll
        for (int b = 0; b < NB_; ++b) pb[nt][b] = 0.f;
    #pragma unroll
    for (int mt = 0; mt < 2; ++mt) {
        int m0 = w * 32 + mt * 16 + hi * 4;
        ushort4 wv[NB_];
        #pragma unroll
        for (int b = 0; b < NB_; ++b)
            wv[b] = *(const ushort4*)(wb1t + b * 256 + m0);
        #pragma unroll
        for (int nt = 0; nt < 4; ++nt) {
            f32x4 r = acc[mt][nt];
            float h0 = silu_fast(r[0]);
            float h1 = silu_fast(r[1]);
            float h2 = silu_fast(r[2]);
            float h3 = silu_fast(r[3]);
            #pragma unroll
            for (int b = 0; b < NB_; ++b) {
                float t = fmaf(h0, bf2f(wv[b].x), fmaf(h1, bf2f(wv[b].y),
                          fmaf(h2, bf2f(wv[b].z), h3 * bf2f(wv[b].w))));
                pb[nt][b] += t;
            }
        }
    }
    #pragma unroll
    for (int off = 16; off <= 32; off <<= 1)
        #pragma unroll
        for (int nt = 0; nt < 4; ++nt)
            #pragma unroll
            for (int b = 0; b < NB_; ++b)
                pb[nt][b] += __shfl_xor(pb[nt][b], off);

    __syncthreads();   // all waves done reading esym region before bonds_part overwrites
    if (hi == 0) {
        #pragma unroll
        for (int nt = 0; nt < 4; ++nt)
            #pragma unroll
            for (int b = 0; b < NB_; ++b)
                bonds_part[(size_t)(w * 64 + nt * 16 + eLo) * NB_ + b] = pb[nt][b];
    }
    __syncthreads();   // bonds_part ready

    for (int idx = tid; idx < 64 * NB_; idx += 512) {
        int edge = idx / NB_, b = idx % NB_;
        float s8 = 0.f;
        #pragma unroll
        for (int pp = 0; pp < 8; ++pp)
            s8 += bonds_part[(size_t)(pp * 64 + edge) * NB_ + b];
        repval[(size_t)(blk * 64 + edge) * NB_ + b] = s8 + b_b1[b];
    }
}

extern "C" void kernel_launch(void* const* d_in, const int* in_sizes, int n_in,
                              void* d_out, int out_size, void* d_ws, size_t ws_size,
                              hipStream_t stream)
{
    const float* s    = (const float*)d_in[0];
    const float* v    = (const float*)d_in[1];
    const float* p    = (const float*)d_in[2];
    const float* e    = (const float*)d_in[3];
    const int*   batch= (const int*)d_in[4];
    const int*   ei   = (const int*)d_in[5];
    const float* W_sm = (const float*)d_in[6];
    const float* b_sm = (const float*)d_in[7];
    const float* W_bm = (const float*)d_in[8];
    const float* b_bm = (const float*)d_in[9];
    const float* W_b0 = (const float*)d_in[10];
    const float* b_b0 = (const float*)d_in[11];
    const float* W_b1 = (const float*)d_in[12];
    const float* b_b1 = (const float*)d_in[13];
    const float* W_c  = (const float*)d_in[14];
    const float* W_a  = (const float*)d_in[15];
    const float* b_a  = (const float*)d_in[16];

    float* out = (float*)d_out;
    float* coords_out = out;                       // 512*3
    float* atoms_out  = out + 1536;                // 512*16
    float* bonds_out  = out + 1536 + 8192;         // 262144*5

    char* ws = (char*)d_ws;
    int*            emap    = (int*)ws;                                  // @0,        1 MB
    unsigned short* s2b     = (unsigned short*)(ws + 0x100000);          // 256 KB
    unsigned short* WfA_bm  = (unsigned short*)(ws + 0x140000);          // 64 KB
    unsigned short* WfA_b0  = (unsigned short*)(ws + 0x150000);          // 128 KB
    float*          cpred   = (float*)(ws + 0x170000);                   // 6 KB
    float*          coords  = (float*)(ws + 0x172000);                   // 6 KB
    float*          zrow    = (float*)(ws + 0x174000);                   // 512 B
    int*            counter = (int*)(ws + 0x175000);                     // 4 B
    int*            pairslot= (int*)(ws + 0x180000);                     // 1 MB
    int4*           worklist= (int4*)(ws + 0x280000);                    // ~2.1 MB
    float*          repval  = (float*)(ws + 0x4B0000);                   // ~2.63 MB

    hipMemsetAsync(emap, 0xFF, N_NODES * N_NODES * sizeof(int), stream); // emap = -1
    hipMemsetAsync(zrow, 0, ED_ * sizeof(float), stream);
    hipMemsetAsync(counter, 0, sizeof(int), stream);

    build_and_pack<<<NE_ / 256 + 48, 256, 0, stream>>>(ei, emap, W_bm, W_b0, WfA_bm, WfA_b0);
    node_kernel8<<<N_NODES / 8, 256, 0, stream>>>(s, v, p, W_sm, b_sm, W_a, b_a, W_c,
                                                  s2b, cpred, atoms_out);
    center_kernel<<<1, 512, 0, stream>>>(cpred, batch, coords, coords_out);
    pair_build<<<(N_NODES * N_NODES) / 256, 256, 0, stream>>>(emap, counter, pairslot, worklist);

    edge_mfma<<<(MAXP + 63) / 64, 512, 0, stream>>>(e, worklist, counter, coords, zrow, s2b,
                                                    WfA_bm, WfA_b0, W_b1,
                                                    b_bm, W_b0 + 256 * SD_, b_b0, b_b1,
                                                    repval);
    bonds_scatter<<<NE_ / 256, 256, 0, stream>>>(ei, pairslot, repval, bonds_out);
}

// Round 10
// 152.594 us; speedup vs baseline: 2.0439x; 1.2214x over previous
//
#include <hip/hip_runtime.h>
#include <math.h>

#define N_NODES 512
#define SD_ 256
#define VD_ 128
#define ED_ 128
#define NE_ 262144
#define NG_ 16
#define NA_ 16
#define NB_ 5
#define MAXP 131328   // N*(N+1)/2 upper bound on distinct unordered pairs

typedef __attribute__((ext_vector_type(8))) short bf16x8;
typedef __attribute__((ext_vector_type(4))) float f32x4;

__device__ __forceinline__ float silu_f(float x) { return x / (1.0f + expf(-x)); }
__device__ __forceinline__ float silu_fast(float x) {
    return x * __builtin_amdgcn_rcpf(1.0f + __builtin_amdgcn_exp2f(x * -1.44269504f));
}
__device__ __forceinline__ unsigned short f2bf(float x) {
    unsigned int u = __float_as_uint(x);
    return (unsigned short)((u + 0x7fffu + ((u >> 16) & 1u)) >> 16);
}
__device__ __forceinline__ float bf2f(unsigned short h) {
    return __uint_as_float(((unsigned int)h) << 16);
}
__device__ __forceinline__ unsigned int cvt_pk_bf16(float lo, float hi) {
    unsigned int r;
    asm("v_cvt_pk_bf16_f32 %0, %1, %2" : "=v"(r) : "v"(lo), "v"(hi));
    return r;
}

__device__ __forceinline__ void pack_one(
    const float* __restrict__ W, unsigned short* __restrict__ out, int nkb, int idx)
{
    int l = idx & 63;
    int kb = (idx >> 6) % nkb;
    int mtg = idx / (64 * nkb);
    int m = mtg * 16 + (l & 15);
    int k0 = kb * 32 + (l >> 4) * 8;
    bf16x8 pack;
    #pragma unroll
    for (int i = 0; i < 8; ++i) pack[i] = (short)f2bf(W[(size_t)(k0 + i) * SD_ + m]);
    *(bf16x8*)(out + (size_t)idx * 8) = pack;
}

// ---------------- Kernel A: fused {map_build | weight pack | node MLP | cpred}
// blocks 0..1023: last-wins emap atomics; 1024..1071: pack W_bm/W_b0 frags;
// 1072..1135: node8 (s2b + atoms); 1136: cpred = p + v@W_c.
__global__ __launch_bounds__(256) void prep_a(
    const int* __restrict__ ei, int* __restrict__ emap,
    const float* __restrict__ W_bm, const float* __restrict__ W_b0,
    unsigned short* __restrict__ WfA_bm, unsigned short* __restrict__ WfA_b0,
    const float* __restrict__ s, const float* __restrict__ v, const float* __restrict__ p,
    const float* __restrict__ W_sm, const float* __restrict__ b_sm,
    const float* __restrict__ W_a, const float* __restrict__ b_a,
    const float* __restrict__ W_c,
    unsigned short* __restrict__ s2b, float* __restrict__ cpred, float* __restrict__ atoms_out)
{
    __shared__ float srow[8][SD_];
    __shared__ float s2row[8][SD_];
    const int bid = blockIdx.x;
    const int tid = threadIdx.x;

    if (bid < 1024) {                       // ---- map_build
        int k = bid * 256 + tid;
        int j = ei[k], i = ei[NE_ + k];
        atomicMax(&emap[j * N_NODES + i], k);
        return;
    }
    if (bid < 1072) {                       // ---- weight pack
        int idx = (bid - 1024) * 256 + tid; // 0..12287
        if (idx < 4096)  pack_one(W_bm, WfA_bm, 4, idx);
        else             pack_one(W_b0, WfA_b0, 8, idx - 4096);
        return;
    }
    if (bid < 1136) {                       // ---- node MLP, 8 nodes/block
        const int n0 = (bid - 1072) * 8;
        #pragma unroll
        for (int n = 0; n < 8; ++n) srow[n][tid] = s[(size_t)(n0 + n) * SD_ + tid];
        __syncthreads();
        float acc[8];
        {
            float bb = b_sm[tid];
            #pragma unroll
            for (int n = 0; n < 8; ++n) acc[n] = bb;
        }
        #pragma unroll 4
        for (int c = 0; c < SD_; ++c) {
            float wv = W_sm[(size_t)c * SD_ + tid];
            #pragma unroll
            for (int n = 0; n < 8; ++n) acc[n] = fmaf(srow[n][c], wv, acc[n]);
        }
        #pragma unroll
        for (int n = 0; n < 8; ++n) {
            float sv = silu_f(acc[n]);
            s2b[(size_t)(n0 + n) * SD_ + tid] = f2bf(sv);
            s2row[n][tid] = sv;
        }
        __syncthreads();
        if (tid < 128) {
            int n = tid >> 4, a = tid & 15;
            float x = b_a[a];
            #pragma unroll 8
            for (int c = 0; c < SD_; ++c) x = fmaf(s2row[n][c], W_a[(size_t)c * NA_ + a], x);
            atoms_out[(size_t)(n0 + n) * NA_ + a] = x;
        }
        return;
    }
    // ---- cpred: 1536 outputs over 256 threads
    for (int o = tid; o < N_NODES * 3; o += 256) {
        float x = p[o];
        const float* vr = v + (size_t)o * VD_;
        #pragma unroll 8
        for (int c = 0; c < VD_; ++c) x = fmaf(vr[c], W_c[c], x);
        cpred[o] = x;
    }
}

// ---------------- Kernel B: fused {center | pair_build}
// block 0: per-graph mean centering; blocks 1..512: unordered-pair compaction.
__global__ __launch_bounds__(512) void prep_b(
    const float* __restrict__ cpred, const int* __restrict__ batch,
    float* __restrict__ coords_ws, float* __restrict__ coords_out,
    const int* __restrict__ emap, int* __restrict__ counter,
    int* __restrict__ pairslot, int4* __restrict__ worklist)
{
    __shared__ float cl[N_NODES * 3];
    __shared__ int   bl[N_NODES];
    __shared__ float meanv[NG_ * 3];
    const int tid = threadIdx.x;

    if (blockIdx.x == 0) {                  // ---- centering (deterministic serial sums)
        bl[tid] = batch[tid];
        #pragma unroll
        for (int dd = 0; dd < 3; ++dd) cl[tid * 3 + dd] = cpred[tid * 3 + dd];
        __syncthreads();
        if (tid < NG_ * 3) {
            int g = tid / 3, dd = tid % 3;
            float sum = 0.f; int cnt = 0;
            for (int n = 0; n < N_NODES; ++n) {
                if (bl[n] == g) { sum += cl[n * 3 + dd]; cnt++; }
            }
            meanv[tid] = sum / (float)(cnt > 0 ? cnt : 1);
        }
        __syncthreads();
        int g = bl[tid];
        #pragma unroll
        for (int dd = 0; dd < 3; ++dd) {
            float val = cl[tid * 3 + dd] - meanv[g * 3 + dd];
            coords_ws[tid * 3 + dd]  = val;
            coords_out[tid * 3 + dd] = val;
        }
        return;
    }
    // ---- pair_build: one thread per (a,b) cell
    int idx = (blockIdx.x - 1) * 512 + tid; // 0..262143
    int a = idx >> 9, b = idx & (N_NODES - 1);
    if (a > b) return;
    int k1 = emap[(a << 9) | b];
    int k2 = emap[(b << 9) | a];
    if (k1 >= 0 || k2 >= 0) {
        int slot = atomicAdd(counter, 1);
        pairslot[(a << 9) | b] = slot;
        pairslot[(b << 9) | a] = slot;
        worklist[slot] = make_int4(a, b, k1, k2);
    }
}

// ---------------- scatter representative bonds to all edges
__global__ __launch_bounds__(256) void bonds_scatter(
    const int* __restrict__ ei, const int* __restrict__ pairslot,
    const float* __restrict__ repval, float* __restrict__ bonds_out)
{
    int k = blockIdx.x * 256 + threadIdx.x;
    int j = ei[k], i = ei[NE_ + k];
    int slot = pairslot[(j << 9) | i];
    const float* rp = repval + (size_t)slot * NB_;
    #pragma unroll
    for (int b = 0; b < NB_; ++b)
        bonds_out[(size_t)k * NB_ + b] = rp[b];
}

// ---------------- Fused edge pipeline over DISTINCT pairs (identical to R9)
__global__ __launch_bounds__(512) void edge_mfma(
    const float* __restrict__ e, const int4* __restrict__ worklist,
    const int* __restrict__ counter, const float* __restrict__ coords,
    const float* __restrict__ zrow, const unsigned short* __restrict__ s2b,
    const unsigned short* __restrict__ WfA_bm, const unsigned short* __restrict__ WfA_b0,
    const float* __restrict__ W_b1,
    const float* __restrict__ b_bm, const float* __restrict__ W_b0_last,
    const float* __restrict__ b_b0, const float* __restrict__ b_b1,
    float* __restrict__ repval)
{
    const int blk = blockIdx.x;
    const int cnt = counter[0];
    if (blk * 64 >= cnt) return;

    __shared__ __align__(16) char smem0[64 * 128 * 2];   // esym (16KB) UNION bonds_part [8][64][5] (10KB)
    __shared__ __align__(16) unsigned short fd_lds[64 * 256]; // 32KB, swizzled [pair][c16^(pair&7)]
    __shared__ unsigned short wb1t[NB_ * 256];
    __shared__ float dw[64];
    __shared__ int li_s[64], lj_s[64];

    unsigned short* esym_lds   = (unsigned short*)smem0;
    float*          bonds_part = (float*)smem0;

    const int tid = threadIdx.x;
    const int l   = tid & 63;
    const int w   = tid >> 6;       // 0..7
    const int eLo = l & 15;
    const int hi  = l >> 4;

    if (tid < 256) {
        // ---- gather + symmetrize (eL = l, q = wave 0..3, 32 floats/thread)
        const int eL = l;
        const int q  = w;           // 0..3
        int widx = min(blk * 64 + eL, cnt - 1);   // tail-clamp: duplicate of last pair
        int4 wk = worklist[widx];
        const float* r1 = (wk.z >= 0) ? (e + (size_t)wk.z * ED_) : zrow;
        const float* r2 = (wk.w >= 0) ? (e + (size_t)wk.w * ED_) : zrow;
        const float4* p1 = (const float4*)(r1 + q * 32);
        const float4* p2 = (const float4*)(r2 + q * 32);
        float4 va[8], vb[8];
        #pragma unroll
        for (int t = 0; t < 8; ++t) va[t] = p1[t];
        #pragma unroll
        for (int t = 0; t < 8; ++t) vb[t] = p2[t];
        #pragma unroll
        for (int t = 0; t < 8; ++t) {
            va[t].x += vb[t].x; va[t].y += vb[t].y;
            va[t].z += vb[t].z; va[t].w += vb[t].w;
        }
        int ntB = eL >> 4, eLoB = eL & 15;
        #pragma unroll
        for (int h2 = 0; h2 < 4; ++h2) {
            float4 x0 = va[h2 * 2], x1 = va[h2 * 2 + 1];
            uint4 c;
            c.x = cvt_pk_bf16(0.5f * x0.x, 0.5f * x0.y);
            c.y = cvt_pk_bf16(0.5f * x0.z, 0.5f * x0.w);
            c.z = cvt_pk_bf16(0.5f * x1.x, 0.5f * x1.y);
            c.w = cvt_pk_bf16(0.5f * x1.z, 0.5f * x1.w);
            int chunk = (ntB * 4 + q) * 64 + h2 * 16 + eLoB;
            *(uint4*)(&esym_lds[chunk * 8]) = c;
        }
    } else {
        // ---- waves 4-7: W_b1 staging + per-pair meta
        int t = tid - 256;          // 0..255
        #pragma unroll
        for (int b = 0; b < NB_; ++b)
            wb1t[b * 256 + t] = f2bf(W_b1[(size_t)t * NB_ + b]);
        if (t < 64) {
            int widx = min(blk * 64 + t, cnt - 1);
            int4 wk = worklist[widx];
            li_s[t] = wk.x; lj_s[t] = wk.y;
            float dx = coords[wk.x * 3 + 0] - coords[wk.y * 3 + 0];
            float dy = coords[wk.x * 3 + 1] - coords[wk.y * 3 + 1];
            float dz = coords[wk.x * 3 + 2] - coords[wk.y * 3 + 2];
            dw[t] = dx * dx + dy * dy + dz * dz;
        }
    }

    // prefetch GEMM1 kb=0 A-frags (strip mtg = w*2+mt)
    bf16x8 a1p[2];
    #pragma unroll
    for (int mt = 0; mt < 2; ++mt)
        a1p[mt] = *(const bf16x8*)(WfA_bm + ((size_t)(((w * 2 + mt) * 4 + 0) * 64 + l) * 8));

    __syncthreads();   // bar1: esym + meta + wb1t ready

    // ---- GEMM1': K=128 (4 k-steps), wave computes 32 cols x 64 pairs
    f32x4 acc[2][4];
    #pragma unroll
    for (int mt = 0; mt < 2; ++mt)
        #pragma unroll
        for (int nt = 0; nt < 4; ++nt) acc[mt][nt] = (f32x4){0.f, 0.f, 0.f, 0.f};

    #pragma unroll
    for (int kb = 0; kb < 4; ++kb) {
        bf16x8 af[2], bfg[4];
        #pragma unroll
        for (int mt = 0; mt < 2; ++mt)
            af[mt] = (kb == 0) ? a1p[mt]
                   : *(const bf16x8*)(WfA_bm + ((size_t)(((w * 2 + mt) * 4 + kb) * 64 + l) * 8));
        #pragma unroll
        for (int nt = 0; nt < 4; ++nt)
            bfg[nt] = *(const bf16x8*)(&esym_lds[(size_t)((nt * 4 + kb) * 64 + l) * 8]);
        __builtin_amdgcn_s_setprio(1);
        #pragma unroll
        for (int mt = 0; mt < 2; ++mt)
            #pragma unroll
            for (int nt = 0; nt < 4; ++nt)
                acc[mt][nt] = __builtin_amdgcn_mfma_f32_16x16x32_bf16(af[mt], bfg[nt], acc[mt][nt], 0, 0, 0);
        __builtin_amdgcn_s_setprio(0);
    }

    // prefetch GEMM2 kb=0 A-frags
    bf16x8 a2p[2];
    #pragma unroll
    for (int mt = 0; mt < 2; ++mt)
        a2p[mt] = *(const bf16x8*)(WfA_b0 + ((size_t)(((w * 2 + mt) * 8 + 0) * 64 + l) * 8));

    // ---- epilogue 1: f = acc + s_a + s_b + b_bm -> swizzled fd (bf16)
    #pragma unroll
    for (int mt = 0; mt < 2; ++mt) {
        int m0 = w * 32 + mt * 16 + hi * 4;
        float4 bb = *(const float4*)(b_bm + m0);
        #pragma unroll
        for (int nt = 0; nt < 4; ++nt) {
            int edge = nt * 16 + eLo;
            int ni = li_s[edge], nj = lj_s[edge];
            ushort4 si = *(const ushort4*)(s2b + (size_t)ni * SD_ + m0);
            ushort4 sj = *(const ushort4*)(s2b + (size_t)nj * SD_ + m0);
            f32x4 r = acc[mt][nt];
            float f0 = r[0] + bf2f(si.x) + bf2f(sj.x) + bb.x;
            float f1 = r[1] + bf2f(si.y) + bf2f(sj.y) + bb.y;
            float f2 = r[2] + bf2f(si.z) + bf2f(sj.z) + bb.z;
            float f3 = r[3] + bf2f(si.w) + bf2f(sj.w) + bb.w;
            uint2 pk;
            pk.x = cvt_pk_bf16(f0, f1);
            pk.y = cvt_pk_bf16(f2, f3);
            int c16 = m0 >> 3;
            int byteo = (edge << 9) + ((c16 ^ (edge & 7)) << 4) + ((m0 & 7) << 1);
            *(uint2*)((char*)fd_lds + byteo) = pk;
        }
    }
    __syncthreads();   // bar2: fd ready

    // ---- GEMM2': K=256 (8 k-steps); init = b_b0 + d * W_b0[row 256]
    #pragma unroll
    for (int mt = 0; mt < 2; ++mt) {
        int m0 = w * 32 + mt * 16 + hi * 4;
        float4 b0 = *(const float4*)(b_b0 + m0);
        float4 w2 = *(const float4*)(W_b0_last + m0);
        #pragma unroll
        for (int nt = 0; nt < 4; ++nt) {
            float dd = dw[nt * 16 + eLo];
            acc[mt][nt] = (f32x4){fmaf(dd, w2.x, b0.x), fmaf(dd, w2.y, b0.y),
                                  fmaf(dd, w2.z, b0.z), fmaf(dd, w2.w, b0.w)};
        }
    }
    #pragma unroll
    for (int kb = 0; kb < 8; ++kb) {
        bf16x8 af[2], bfg[4];
        #pragma unroll
        for (int mt = 0; mt < 2; ++mt)
            af[mt] = (kb == 0) ? a2p[mt]
                   : *(const bf16x8*)(WfA_b0 + ((size_t)(((w * 2 + mt) * 8 + kb) * 64 + l) * 8));
        #pragma unroll
        for (int nt = 0; nt < 4; ++nt) {
            int edge = nt * 16 + eLo;
            int c16 = (kb << 2) + hi;
            int byteo = (edge << 9) + ((c16 ^ (edge & 7)) << 4);
            bfg[nt] = *(const bf16x8*)((const char*)fd_lds + byteo);
        }
        __builtin_amdgcn_s_setprio(1);
        #pragma unroll
        for (int mt = 0; mt < 2; ++mt)
            #pragma unroll
            for (int nt = 0; nt < 4; ++nt)
                acc[mt][nt] = __builtin_amdgcn_mfma_f32_16x16x32_bf16(af[mt], bfg[nt], acc[mt][nt], 0, 0, 0);
        __builtin_amdgcn_s_setprio(0);
    }

    // ---- bonds: h = silu(pre) fp32, dot with W_b1 (bf16), reduce over strip cols
    float pb[4][NB_];
    #pragma unroll
    for (int nt = 0; nt < 4; ++nt)
        #pragma unroll
        for (int b = 0; b < NB_; ++b) pb[nt][b] = 0.f;
    #pragma unroll
    for (int mt = 0; mt < 2; ++mt) {
        int m0 = w * 32 + mt * 16 + hi * 4;
        ushort4 wv[NB_];
        #pragma unroll
        for (int b = 0; b < NB_; ++b)
            wv[b] = *(const ushort4*)(wb1t + b * 256 + m0);
        #pragma unroll
        for (int nt = 0; nt < 4; ++nt) {
            f32x4 r = acc[mt][nt];
            float h0 = silu_fast(r[0]);
            float h1 = silu_fast(r[1]);
            float h2 = silu_fast(r[2]);
            float h3 = silu_fast(r[3]);
            #pragma unroll
            for (int b = 0; b < NB_; ++b) {
                float t = fmaf(h0, bf2f(wv[b].x), fmaf(h1, bf2f(wv[b].y),
                          fmaf(h2, bf2f(wv[b].z), h3 * bf2f(wv[b].w))));
                pb[nt][b] += t;
            }
        }
    }
    #pragma unroll
    for (int off = 16; off <= 32; off <<= 1)
        #pragma unroll
        for (int nt = 0; nt < 4; ++nt)
            #pragma unroll
            for (int b = 0; b < NB_; ++b)
                pb[nt][b] += __shfl_xor(pb[nt][b], off);

    __syncthreads();   // all waves done reading esym region before bonds_part overwrites
    if (hi == 0) {
        #pragma unroll
        for (int nt = 0; nt < 4; ++nt)
            #pragma unroll
            for (int b = 0; b < NB_; ++b)
                bonds_part[(size_t)(w * 64 + nt * 16 + eLo) * NB_ + b] = pb[nt][b];
    }
    __syncthreads();   // bonds_part ready

    for (int idx = tid; idx < 64 * NB_; idx += 512) {
        int edge = idx / NB_, b = idx % NB_;
        float s8 = 0.f;
        #pragma unroll
        for (int pp = 0; pp < 8; ++pp)
            s8 += bonds_part[(size_t)(pp * 64 + edge) * NB_ + b];
        repval[(size_t)(blk * 64 + edge) * NB_ + b] = s8 + b_b1[b];
    }
}

extern "C" void kernel_launch(void* const* d_in, const int* in_sizes, int n_in,
                              void* d_out, int out_size, void* d_ws, size_t ws_size,
                              hipStream_t stream)
{
    const float* s    = (const float*)d_in[0];
    const float* v    = (const float*)d_in[1];
    const float* p    = (const float*)d_in[2];
    const float* e    = (const float*)d_in[3];
    const int*   batch= (const int*)d_in[4];
    const int*   ei   = (const int*)d_in[5];
    const float* W_sm = (const float*)d_in[6];
    const float* b_sm = (const float*)d_in[7];
    const float* W_bm = (const float*)d_in[8];
    const float* b_bm = (const float*)d_in[9];
    const float* W_b0 = (const float*)d_in[10];
    const float* b_b0 = (const float*)d_in[11];
    const float* W_b1 = (const float*)d_in[12];
    const float* b_b1 = (const float*)d_in[13];
    const float* W_c  = (const float*)d_in[14];
    const float* W_a  = (const float*)d_in[15];
    const float* b_a  = (const float*)d_in[16];

    float* out = (float*)d_out;
    float* coords_out = out;                       // 512*3
    float* atoms_out  = out + 1536;                // 512*16
    float* bonds_out  = out + 1536 + 8192;         // 262144*5

    char* ws = (char*)d_ws;
    int*            emap    = (int*)ws;                                  // @0,        1 MB
    unsigned short* s2b     = (unsigned short*)(ws + 0x100000);          // 256 KB
    unsigned short* WfA_bm  = (unsigned short*)(ws + 0x140000);          // 64 KB
    unsigned short* WfA_b0  = (unsigned short*)(ws + 0x150000);          // 128 KB
    float*          cpred   = (float*)(ws + 0x170000);                   // 6 KB
    float*          coords  = (float*)(ws + 0x172000);                   // 6 KB
    int*            counter = (int*)(ws + 0x175000);                     // 4 B
    float*          zrow    = (float*)(ws + 0x175100);                   // 512 B
    int*            pairslot= (int*)(ws + 0x180000);                     // 1 MB
    int4*           worklist= (int4*)(ws + 0x280000);                    // ~2.1 MB
    float*          repval  = (float*)(ws + 0x4B0000);                   // ~2.63 MB

    hipMemsetAsync(emap, 0xFF, N_NODES * N_NODES * sizeof(int), stream); // emap = -1
    hipMemsetAsync(ws + 0x175000, 0, 0x300, stream);                     // counter + zrow

    prep_a<<<1137, 256, 0, stream>>>(ei, emap, W_bm, W_b0, WfA_bm, WfA_b0,
                                     s, v, p, W_sm, b_sm, W_a, b_a, W_c,
                                     s2b, cpred, atoms_out);
    prep_b<<<513, 512, 0, stream>>>(cpred, batch, coords, coords_out,
                                    emap, counter, pairslot, worklist);

    edge_mfma<<<(MAXP + 63) / 64, 512, 0, stream>>>(e, worklist, counter, coords, zrow, s2b,
                                                    WfA_bm, WfA_b0, W_b1,
                                                    b_bm, W_b0 + 256 * SD_, b_b0, b_b1,
                                                    repval);
    bonds_scatter<<<NE_ / 256, 256, 0, stream>>>(ei, pairslot, repval, bonds_out);
}

// Round 11
// 151.377 us; speedup vs baseline: 2.0603x; 1.0080x over previous
//
#include <hip/hip_runtime.h>
#include <math.h>

#define N_NODES 512
#define SD_ 256
#define VD_ 128
#define ED_ 128
#define NE_ 262144
#define NG_ 16
#define NA_ 16
#define NB_ 5
#define MAXP 131328   // N*(N+1)/2 upper bound on distinct unordered pairs

typedef __attribute__((ext_vector_type(8))) short bf16x8;
typedef __attribute__((ext_vector_type(4))) float f32x4;

__device__ __forceinline__ float silu_f(float x) { return x / (1.0f + expf(-x)); }
__device__ __forceinline__ float silu_fast(float x) {
    return x * __builtin_amdgcn_rcpf(1.0f + __builtin_amdgcn_exp2f(x * -1.44269504f));
}
__device__ __forceinline__ unsigned short f2bf(float x) {
    unsigned int u = __float_as_uint(x);
    return (unsigned short)((u + 0x7fffu + ((u >> 16) & 1u)) >> 16);
}
__device__ __forceinline__ float bf2f(unsigned short h) {
    return __uint_as_float(((unsigned int)h) << 16);
}
__device__ __forceinline__ unsigned int cvt_pk_bf16(float lo, float hi) {
    unsigned int r;
    asm("v_cvt_pk_bf16_f32 %0, %1, %2" : "=v"(r) : "v"(lo), "v"(hi));
    return r;
}

__device__ __forceinline__ void pack_one(
    const float* __restrict__ W, unsigned short* __restrict__ out, int nkb, int idx)
{
    int l = idx & 63;
    int kb = (idx >> 6) % nkb;
    int mtg = idx / (64 * nkb);
    int m = mtg * 16 + (l & 15);
    int k0 = kb * 32 + (l >> 4) * 8;
    bf16x8 pack;
    #pragma unroll
    for (int i = 0; i < 8; ++i) pack[i] = (short)f2bf(W[(size_t)(k0 + i) * SD_ + m]);
    *(bf16x8*)(out + (size_t)idx * 8) = pack;
}

// ---------------- Kernel A: fused {map_build | weight pack | node MLP | cpred+init}
// blocks 0..1023: last-wins emap atomics; 1024..1071: pack W_bm/W_b0 frags;
// 1072..1327: node MLP, 2 nodes/block (R11: 256 blocks for TLP, was 64);
// 1328: cpred = p + v@W_c, plus counter/zrow zero-init (replaces a memset node).
__global__ __launch_bounds__(256) void prep_a(
    const int* __restrict__ ei, int* __restrict__ emap,
    const float* __restrict__ W_bm, const float* __restrict__ W_b0,
    unsigned short* __restrict__ WfA_bm, unsigned short* __restrict__ WfA_b0,
    const float* __restrict__ s, const float* __restrict__ v, const float* __restrict__ p,
    const float* __restrict__ W_sm, const float* __restrict__ b_sm,
    const float* __restrict__ W_a, const float* __restrict__ b_a,
    const float* __restrict__ W_c,
    unsigned short* __restrict__ s2b, float* __restrict__ cpred, float* __restrict__ atoms_out,
    int* __restrict__ counter, float* __restrict__ zrow)
{
    __shared__ float srow[2][SD_];
    __shared__ float s2row[2][SD_];
    const int bid = blockIdx.x;
    const int tid = threadIdx.x;

    if (bid < 1024) {                       // ---- map_build
        int k = bid * 256 + tid;
        int j = ei[k], i = ei[NE_ + k];
        atomicMax(&emap[j * N_NODES + i], k);
        return;
    }
    if (bid < 1072) {                       // ---- weight pack
        int idx = (bid - 1024) * 256 + tid; // 0..12287
        if (idx < 4096)  pack_one(W_bm, WfA_bm, 4, idx);
        else             pack_one(W_b0, WfA_b0, 8, idx - 4096);
        return;
    }
    if (bid < 1328) {                       // ---- node MLP, 2 nodes/block
        const int n0 = (bid - 1072) * 2;
        #pragma unroll
        for (int n = 0; n < 2; ++n) srow[n][tid] = s[(size_t)(n0 + n) * SD_ + tid];
        __syncthreads();
        float acc[2];
        {
            float bb = b_sm[tid];
            acc[0] = bb; acc[1] = bb;
        }
        #pragma unroll 8
        for (int c = 0; c < SD_; ++c) {
            float wv = W_sm[(size_t)c * SD_ + tid];
            acc[0] = fmaf(srow[0][c], wv, acc[0]);
            acc[1] = fmaf(srow[1][c], wv, acc[1]);
        }
        #pragma unroll
        for (int n = 0; n < 2; ++n) {
            float sv = silu_f(acc[n]);
            s2b[(size_t)(n0 + n) * SD_ + tid] = f2bf(sv);
            s2row[n][tid] = sv;
        }
        __syncthreads();
        if (tid < 32) {
            int n = tid >> 4, a = tid & 15;
            float x = b_a[a];
            #pragma unroll 8
            for (int c = 0; c < SD_; ++c) x = fmaf(s2row[n][c], W_a[(size_t)c * NA_ + a], x);
            atoms_out[(size_t)(n0 + n) * NA_ + a] = x;
        }
        return;
    }
    // ---- block 1328: cpred (1536 outputs) + counter/zrow init
    if (tid == 0) counter[0] = 0;
    if (tid < ED_) zrow[tid] = 0.0f;
    for (int o = tid; o < N_NODES * 3; o += 256) {
        float x = p[o];
        const float* vr = v + (size_t)o * VD_;
        #pragma unroll 8
        for (int c = 0; c < VD_; ++c) x = fmaf(vr[c], W_c[c], x);
        cpred[o] = x;
    }
}

// ---------------- Kernel B: fused {center | pair_build}
__global__ __launch_bounds__(512) void prep_b(
    const float* __restrict__ cpred, const int* __restrict__ batch,
    float* __restrict__ coords_ws, float* __restrict__ coords_out,
    const int* __restrict__ emap, int* __restrict__ counter,
    int* __restrict__ pairslot, int4* __restrict__ worklist)
{
    __shared__ float cl[N_NODES * 3];
    __shared__ int   bl[N_NODES];
    __shared__ float meanv[NG_ * 3];
    const int tid = threadIdx.x;

    if (blockIdx.x == 0) {                  // ---- centering (deterministic serial sums)
        bl[tid] = batch[tid];
        #pragma unroll
        for (int dd = 0; dd < 3; ++dd) cl[tid * 3 + dd] = cpred[tid * 3 + dd];
        __syncthreads();
        if (tid < NG_ * 3) {
            int g = tid / 3, dd = tid % 3;
            float sum = 0.f; int cnt = 0;
            for (int n = 0; n < N_NODES; ++n) {
                if (bl[n] == g) { sum += cl[n * 3 + dd]; cnt++; }
            }
            meanv[tid] = sum / (float)(cnt > 0 ? cnt : 1);
        }
        __syncthreads();
        int g = bl[tid];
        #pragma unroll
        for (int dd = 0; dd < 3; ++dd) {
            float val = cl[tid * 3 + dd] - meanv[g * 3 + dd];
            coords_ws[tid * 3 + dd]  = val;
            coords_out[tid * 3 + dd] = val;
        }
        return;
    }
    // ---- pair_build: one thread per (a,b) cell
    int idx = (blockIdx.x - 1) * 512 + tid; // 0..262143
    int a = idx >> 9, b = idx & (N_NODES - 1);
    if (a > b) return;
    int k1 = emap[(a << 9) | b];
    int k2 = emap[(b << 9) | a];
    if (k1 >= 0 || k2 >= 0) {
        int slot = atomicAdd(counter, 1);
        pairslot[(a << 9) | b] = slot;
        pairslot[(b << 9) | a] = slot;
        worklist[slot] = make_int4(a, b, k1, k2);
    }
}

// ---------------- scatter representative bonds to all edges (R11: 5 threads/edge)
__global__ __launch_bounds__(256) void bonds_scatter(
    const int* __restrict__ ei, const int* __restrict__ pairslot,
    const float* __restrict__ repval, const float* __restrict__ b_b1,
    float* __restrict__ bonds_out)
{
    int idx = blockIdx.x * 256 + threadIdx.x;   // 0 .. NE*5-1
    int k = idx / NB_;
    int b = idx - k * NB_;
    int j = ei[k], i = ei[NE_ + k];
    int slot = pairslot[(j << 9) | i];
    bonds_out[idx] = repval[(size_t)slot * NB_ + b];
}

// ---------------- Fused edge pipeline over DISTINCT pairs
// R11: full GEMM1 A-frag prefetch (a1pf[4][2], +24 VGPR within the 85-VGPR
// free headroom at 3 blocks/CU). Otherwise identical to R9/R10.
__global__ __launch_bounds__(512) void edge_mfma(
    const float* __restrict__ e, const int4* __restrict__ worklist,
    const int* __restrict__ counter, const float* __restrict__ coords,
    const float* __restrict__ zrow, const unsigned short* __restrict__ s2b,
    const unsigned short* __restrict__ WfA_bm, const unsigned short* __restrict__ WfA_b0,
    const float* __restrict__ W_b1,
    const float* __restrict__ b_bm, const float* __restrict__ W_b0_last,
    const float* __restrict__ b_b0, const float* __restrict__ b_b1,
    float* __restrict__ repval)
{
    const int blk = blockIdx.x;
    const int cnt = counter[0];
    if (blk * 64 >= cnt) return;

    __shared__ __align__(16) char smem0[64 * 128 * 2];   // esym (16KB) UNION bonds_part [8][64][5] (10KB)
    __shared__ __align__(16) unsigned short fd_lds[64 * 256]; // 32KB, swizzled [pair][c16^(pair&7)]
    __shared__ unsigned short wb1t[NB_ * 256];
    __shared__ float dw[64];
    __shared__ int li_s[64], lj_s[64];

    unsigned short* esym_lds   = (unsigned short*)smem0;
    float*          bonds_part = (float*)smem0;

    const int tid = threadIdx.x;
    const int l   = tid & 63;
    const int w   = tid >> 6;       // 0..7
    const int eLo = l & 15;
    const int hi  = l >> 4;

    // prefetch ALL GEMM1 A-frags (L2-hot, no LDS dependency) — issued first
    bf16x8 a1pf[4][2];
    #pragma unroll
    for (int kb = 0; kb < 4; ++kb)
        #pragma unroll
        for (int mt = 0; mt < 2; ++mt)
            a1pf[kb][mt] = *(const bf16x8*)(WfA_bm + ((size_t)(((w * 2 + mt) * 4 + kb) * 64 + l) * 8));

    if (tid < 256) {
        // ---- gather + symmetrize (eL = l, q = wave 0..3, 32 floats/thread)
        const int eL = l;
        const int q  = w;           // 0..3
        int widx = min(blk * 64 + eL, cnt - 1);   // tail-clamp: duplicate of last pair
        int4 wk = worklist[widx];
        const float* r1 = (wk.z >= 0) ? (e + (size_t)wk.z * ED_) : zrow;
        const float* r2 = (wk.w >= 0) ? (e + (size_t)wk.w * ED_) : zrow;
        const float4* p1 = (const float4*)(r1 + q * 32);
        const float4* p2 = (const float4*)(r2 + q * 32);
        float4 va[8], vb[8];
        #pragma unroll
        for (int t = 0; t < 8; ++t) va[t] = p1[t];
        #pragma unroll
        for (int t = 0; t < 8; ++t) vb[t] = p2[t];
        #pragma unroll
        for (int t = 0; t < 8; ++t) {
            va[t].x += vb[t].x; va[t].y += vb[t].y;
            va[t].z += vb[t].z; va[t].w += vb[t].w;
        }
        int ntB = eL >> 4, eLoB = eL & 15;
        #pragma unroll
        for (int h2 = 0; h2 < 4; ++h2) {
            float4 x0 = va[h2 * 2], x1 = va[h2 * 2 + 1];
            uint4 c;
            c.x = cvt_pk_bf16(0.5f * x0.x, 0.5f * x0.y);
            c.y = cvt_pk_bf16(0.5f * x0.z, 0.5f * x0.w);
            c.z = cvt_pk_bf16(0.5f * x1.x, 0.5f * x1.y);
            c.w = cvt_pk_bf16(0.5f * x1.z, 0.5f * x1.w);
            int chunk = (ntB * 4 + q) * 64 + h2 * 16 + eLoB;
            *(uint4*)(&esym_lds[chunk * 8]) = c;
        }
    } else {
        // ---- waves 4-7: W_b1 staging + per-pair meta
        int t = tid - 256;          // 0..255
        #pragma unroll
        for (int b = 0; b < NB_; ++b)
            wb1t[b * 256 + t] = f2bf(W_b1[(size_t)t * NB_ + b]);
        if (t < 64) {
            int widx = min(blk * 64 + t, cnt - 1);
            int4 wk = worklist[widx];
            li_s[t] = wk.x; lj_s[t] = wk.y;
            float dx = coords[wk.x * 3 + 0] - coords[wk.y * 3 + 0];
            float dy = coords[wk.x * 3 + 1] - coords[wk.y * 3 + 1];
            float dz = coords[wk.x * 3 + 2] - coords[wk.y * 3 + 2];
            dw[t] = dx * dx + dy * dy + dz * dz;
        }
    }

    __syncthreads();   // bar1: esym + meta + wb1t ready

    // ---- GEMM1': K=128 (4 k-steps), wave computes 32 cols x 64 pairs
    f32x4 acc[2][4];
    #pragma unroll
    for (int mt = 0; mt < 2; ++mt)
        #pragma unroll
        for (int nt = 0; nt < 4; ++nt) acc[mt][nt] = (f32x4){0.f, 0.f, 0.f, 0.f};

    #pragma unroll
    for (int kb = 0; kb < 4; ++kb) {
        bf16x8 bfg[4];
        #pragma unroll
        for (int nt = 0; nt < 4; ++nt)
            bfg[nt] = *(const bf16x8*)(&esym_lds[(size_t)((nt * 4 + kb) * 64 + l) * 8]);
        __builtin_amdgcn_s_setprio(1);
        #pragma unroll
        for (int mt = 0; mt < 2; ++mt)
            #pragma unroll
            for (int nt = 0; nt < 4; ++nt)
                acc[mt][nt] = __builtin_amdgcn_mfma_f32_16x16x32_bf16(a1pf[kb][mt], bfg[nt], acc[mt][nt], 0, 0, 0);
        __builtin_amdgcn_s_setprio(0);
    }

    // prefetch GEMM2 kb=0 A-frags
    bf16x8 a2p[2];
    #pragma unroll
    for (int mt = 0; mt < 2; ++mt)
        a2p[mt] = *(const bf16x8*)(WfA_b0 + ((size_t)(((w * 2 + mt) * 8 + 0) * 64 + l) * 8));

    // ---- epilogue 1: f = acc + s_a + s_b + b_bm -> swizzled fd (bf16)
    #pragma unroll
    for (int mt = 0; mt < 2; ++mt) {
        int m0 = w * 32 + mt * 16 + hi * 4;
        float4 bb = *(const float4*)(b_bm + m0);
        #pragma unroll
        for (int nt = 0; nt < 4; ++nt) {
            int edge = nt * 16 + eLo;
            int ni = li_s[edge], nj = lj_s[edge];
            ushort4 si = *(const ushort4*)(s2b + (size_t)ni * SD_ + m0);
            ushort4 sj = *(const ushort4*)(s2b + (size_t)nj * SD_ + m0);
            f32x4 r = acc[mt][nt];
            float f0 = r[0] + bf2f(si.x) + bf2f(sj.x) + bb.x;
            float f1 = r[1] + bf2f(si.y) + bf2f(sj.y) + bb.y;
            float f2 = r[2] + bf2f(si.z) + bf2f(sj.z) + bb.z;
            float f3 = r[3] + bf2f(si.w) + bf2f(sj.w) + bb.w;
            uint2 pk;
            pk.x = cvt_pk_bf16(f0, f1);
            pk.y = cvt_pk_bf16(f2, f3);
            int c16 = m0 >> 3;
            int byteo = (edge << 9) + ((c16 ^ (edge & 7)) << 4) + ((m0 & 7) << 1);
            *(uint2*)((char*)fd_lds + byteo) = pk;
        }
    }
    __syncthreads();   // bar2: fd ready

    // ---- GEMM2': K=256 (8 k-steps); init = b_b0 + d * W_b0[row 256]
    #pragma unroll
    for (int mt = 0; mt < 2; ++mt) {
        int m0 = w * 32 + mt * 16 + hi * 4;
        float4 b0 = *(const float4*)(b_b0 + m0);
        float4 w2 = *(const float4*)(W_b0_last + m0);
        #pragma unroll
        for (int nt = 0; nt < 4; ++nt) {
            float dd = dw[nt * 16 + eLo];
            acc[mt][nt] = (f32x4){fmaf(dd, w2.x, b0.x), fmaf(dd, w2.y, b0.y),
                                  fmaf(dd, w2.z, b0.z), fmaf(dd, w2.w, b0.w)};
        }
    }
    #pragma unroll
    for (int kb = 0; kb < 8; ++kb) {
        bf16x8 af[2], bfg[4];
        #pragma unroll
        for (int mt = 0; mt < 2; ++mt)
            af[mt] = (kb == 0) ? a2p[mt]
                   : *(const bf16x8*)(WfA_b0 + ((size_t)(((w * 2 + mt) * 8 + kb) * 64 + l) * 8));
        #pragma unroll
        for (int nt = 0; nt < 4; ++nt) {
            int edge = nt * 16 + eLo;
            int c16 = (kb << 2) + hi;
            int byteo = (edge << 9) + ((c16 ^ (edge & 7)) << 4);
            bfg[nt] = *(const bf16x8*)((const char*)fd_lds + byteo);
        }
        __builtin_amdgcn_s_setprio(1);
        #pragma unroll
        for (int mt = 0; mt < 2; ++mt)
            #pragma unroll
            for (int nt = 0; nt < 4; ++nt)
                acc[mt][nt] = __builtin_amdgcn_mfma_f32_16x16x32_bf16(af[mt], bfg[nt], acc[mt][nt], 0, 0, 0);
        __builtin_amdgcn_s_setprio(0);
    }

    // ---- bonds: h = silu(pre) fp32, dot with W_b1 (bf16), reduce over strip cols
    float pb[4][NB_];
    #pragma unroll
    for (int nt = 0; nt < 4; ++nt)
        #pragma unroll
        for (int b = 0; b < NB_; ++b) pb[nt][b] = 0.f;
    #pragma unroll
    for (int mt = 0; mt < 2; ++mt) {
        int m0 = w * 32 + mt * 16 + hi * 4;
        ushort4 wv[NB_];
        #pragma unroll
        for (int b = 0; b < NB_; ++b)
            wv[b] = *(const ushort4*)(wb1t + b * 256 + m0);
        #pragma unroll
        for (int nt = 0; nt < 4; ++nt) {
            f32x4 r = acc[mt][nt];
            float h0 = silu_fast(r[0]);
            float h1 = silu_fast(r[1]);
            float h2 = silu_fast(r[2]);
            float h3 = silu_fast(r[3]);
            #pragma unroll
            for (int b = 0; b < NB_; ++b) {
                float t = fmaf(h0, bf2f(wv[b].x), fmaf(h1, bf2f(wv[b].y),
                          fmaf(h2, bf2f(wv[b].z), h3 * bf2f(wv[b].w))));
                pb[nt][b] += t;
            }
        }
    }
    #pragma unroll
    for (int off = 16; off <= 32; off <<= 1)
        #pragma unroll
        for (int nt = 0; nt < 4; ++nt)
            #pragma unroll
            for (int b = 0; b < NB_; ++b)
                pb[nt][b] += __shfl_xor(pb[nt][b], off);

    __syncthreads();   // all waves done reading esym region before bonds_part overwrites
    if (hi == 0) {
        #pragma unroll
        for (int nt = 0; nt < 4; ++nt)
            #pragma unroll
            for (int b = 0; b < NB_; ++b)
                bonds_part[(size_t)(w * 64 + nt * 16 + eLo) * NB_ + b] = pb[nt][b];
    }
    __syncthreads();   // bonds_part ready

    for (int idx = tid; idx < 64 * NB_; idx += 512) {
        int edge = idx / NB_, b = idx % NB_;
        float s8 = 0.f;
        #pragma unroll
        for (int pp = 0; pp < 8; ++pp)
            s8 += bonds_part[(size_t)(pp * 64 + edge) * NB_ + b];
        repval[(size_t)(blk * 64 + edge) * NB_ + b] = s8 + b_b1[b];
    }
}

extern "C" void kernel_launch(void* const* d_in, const int* in_sizes, int n_in,
                              void* d_out, int out_size, void* d_ws, size_t ws_size,
                              hipStream_t stream)
{
    const float* s    = (const float*)d_in[0];
    const float* v    = (const float*)d_in[1];
    const float* p    = (const float*)d_in[2];
    const float* e    = (const float*)d_in[3];
    const int*   batch= (const int*)d_in[4];
    const int*   ei   = (const int*)d_in[5];
    const float* W_sm = (const float*)d_in[6];
    const float* b_sm = (const float*)d_in[7];
    const float* W_bm = (const float*)d_in[8];
    const float* b_bm = (const float*)d_in[9];
    const float* W_b0 = (const float*)d_in[10];
    const float* b_b0 = (const float*)d_in[11];
    const float* W_b1 = (const float*)d_in[12];
    const float* b_b1 = (const float*)d_in[13];
    const float* W_c  = (const float*)d_in[14];
    const float* W_a  = (const float*)d_in[15];
    const float* b_a  = (const float*)d_in[16];

    float* out = (float*)d_out;
    float* coords_out = out;                       // 512*3
    float* atoms_out  = out + 1536;                // 512*16
    float* bonds_out  = out + 1536 + 8192;         // 262144*5

    char* ws = (char*)d_ws;
    int*            emap    = (int*)ws;                                  // @0,        1 MB
    unsigned short* s2b     = (unsigned short*)(ws + 0x100000);          // 256 KB
    unsigned short* WfA_bm  = (unsigned short*)(ws + 0x140000);          // 64 KB
    unsigned short* WfA_b0  = (unsigned short*)(ws + 0x150000);          // 128 KB
    float*          cpred   = (float*)(ws + 0x170000);                   // 6 KB
    float*          coords  = (float*)(ws + 0x172000);                   // 6 KB
    int*            counter = (int*)(ws + 0x175000);                     // 4 B
    float*          zrow    = (float*)(ws + 0x175100);                   // 512 B
    int*            pairslot= (int*)(ws + 0x180000);                     // 1 MB
    int4*           worklist= (int4*)(ws + 0x280000);                    // ~2.1 MB
    float*          repval  = (float*)(ws + 0x4B0000);                   // ~2.63 MB

    hipMemsetAsync(emap, 0xFF, N_NODES * N_NODES * sizeof(int), stream); // emap = -1

    prep_a<<<1329, 256, 0, stream>>>(ei, emap, W_bm, W_b0, WfA_bm, WfA_b0,
                                     s, v, p, W_sm, b_sm, W_a, b_a, W_c,
                                     s2b, cpred, atoms_out, counter, zrow);
    prep_b<<<513, 512, 0, stream>>>(cpred, batch, coords, coords_out,
                                    emap, counter, pairslot, worklist);

    edge_mfma<<<(MAXP + 63) / 64, 512, 0, stream>>>(e, worklist, counter, coords, zrow, s2b,
                                                    WfA_bm, WfA_b0, W_b1,
                                                    b_bm, W_b0 + 256 * SD_, b_b0, b_b1,
                                                    repval);
    bonds_scatter<<<NE_ * NB_ / 256, 256, 0, stream>>>(ei, pairslot, repval, b_b1, bonds_out);
}